// Round 1
// baseline (2496.648 us; speedup 1.0000x reference)
//
#include <hip/hip_runtime.h>
#include <math.h>

#define B_  4
#define S_  2048
#define D_  512
#define H_  8
#define FF_ 2048
#define W_  128
#define DH_ 64
#define NW_ 16
#define TRD (3*D_)   // 1536

// ---------------------------------------------------------------------------
// Generic fp32 GEMM: C[M,N] = A[M,K] @ W[N,K]^T (+bias) (+relu)
// A row-major with leading dim lda; W row-major [N,K]; C leading dim ldc.
// Grid: (N/128, M/128), block 256. M,N multiples of 128; K multiple of 16.
// ---------------------------------------------------------------------------
__global__ __launch_bounds__(256) void gemm_kernel(
    const float* __restrict__ A, int lda,
    const float* __restrict__ Wt,
    const float* __restrict__ bias,
    float* __restrict__ C, int ldc,
    int K, int relu)
{
    __shared__ float As[16][132];
    __shared__ float Ws[16][132];
    const int tid = threadIdx.x;
    const int bm = blockIdx.y * 128;
    const int bn = blockIdx.x * 128;
    const int tx = tid & 15;
    const int ty = tid >> 4;
    const int mBase = ty * 8;
    const int nBase = tx * 8;

    float acc[8][8];
    #pragma unroll
    for (int i = 0; i < 8; i++)
        #pragma unroll
        for (int j = 0; j < 8; j++) acc[i][j] = 0.f;

    for (int k0 = 0; k0 < K; k0 += 16) {
        #pragma unroll
        for (int i = 0; i < 2; i++) {
            int idx = tid + i * 256;          // 0..511
            int row = idx >> 2;               // 0..127
            int kc  = (idx & 3) << 2;         // 0,4,8,12
            float4 va = *(const float4*)(A + (size_t)(bm + row) * lda + (k0 + kc));
            As[kc + 0][row] = va.x; As[kc + 1][row] = va.y;
            As[kc + 2][row] = va.z; As[kc + 3][row] = va.w;
            float4 vw = *(const float4*)(Wt + (size_t)(bn + row) * K + (k0 + kc));
            Ws[kc + 0][row] = vw.x; Ws[kc + 1][row] = vw.y;
            Ws[kc + 2][row] = vw.z; Ws[kc + 3][row] = vw.w;
        }
        __syncthreads();
        #pragma unroll
        for (int kk = 0; kk < 16; kk++) {
            float a[8], b[8];
            *(float4*)&a[0] = *(const float4*)&As[kk][mBase];
            *(float4*)&a[4] = *(const float4*)&As[kk][mBase + 4];
            *(float4*)&b[0] = *(const float4*)&Ws[kk][nBase];
            *(float4*)&b[4] = *(const float4*)&Ws[kk][nBase + 4];
            #pragma unroll
            for (int i = 0; i < 8; i++)
                #pragma unroll
                for (int j = 0; j < 8; j++)
                    acc[i][j] = fmaf(a[i], b[j], acc[i][j]);
        }
        __syncthreads();
    }

    float bvals[8];
    #pragma unroll
    for (int j = 0; j < 8; j++) bvals[j] = bias ? bias[bn + nBase + j] : 0.f;
    #pragma unroll
    for (int i = 0; i < 8; i++) {
        size_t m = (size_t)(bm + mBase + i);
        float t[8];
        #pragma unroll
        for (int j = 0; j < 8; j++) {
            float v = acc[i][j] + bvals[j];
            if (relu) v = v > 0.f ? v : 0.f;
            t[j] = v;
        }
        *(float4*)(C + m * ldc + bn + nBase)     = make_float4(t[0], t[1], t[2], t[3]);
        *(float4*)(C + m * ldc + bn + nBase + 4) = make_float4(t[4], t[5], t[6], t[7]);
    }
}

// ---------------------------------------------------------------------------
// Wave(64)-per-row LayerNorm over D=512; optional second input added first.
// Block 256 = 4 independent waves = 4 rows. Grid: rows/4.
// ---------------------------------------------------------------------------
__device__ __forceinline__ float wave_sum64(float v) {
    #pragma unroll
    for (int off = 32; off > 0; off >>= 1) v += __shfl_xor(v, off, 64);
    return v;
}

__global__ __launch_bounds__(256) void addln_kernel(
    const float* __restrict__ a, const float* __restrict__ b,
    const float* __restrict__ g, const float* __restrict__ be,
    float* __restrict__ out)
{
    const int lane = threadIdx.x & 63;
    const int row  = blockIdx.x * 4 + (threadIdx.x >> 6);
    const size_t base = (size_t)row * D_ + lane * 8;
    float v[8];
    *(float4*)&v[0] = *(const float4*)(a + base);
    *(float4*)&v[4] = *(const float4*)(a + base + 4);
    if (b) {
        float w[8];
        *(float4*)&w[0] = *(const float4*)(b + base);
        *(float4*)&w[4] = *(const float4*)(b + base + 4);
        #pragma unroll
        for (int i = 0; i < 8; i++) v[i] += w[i];
    }
    float s = 0.f;
    #pragma unroll
    for (int i = 0; i < 8; i++) s += v[i];
    float mean = wave_sum64(s) * (1.0f / 512.0f);
    float vs = 0.f;
    #pragma unroll
    for (int i = 0; i < 8; i++) { float d = v[i] - mean; vs += d * d; }
    float var = wave_sum64(vs) * (1.0f / 512.0f);
    float r = rsqrtf(var + 1e-5f);
    const int c = lane * 8;
    float t[8];
    #pragma unroll
    for (int i = 0; i < 8; i++) t[i] = (v[i] - mean) * r * g[c + i] + be[c + i];
    *(float4*)(out + base)     = make_float4(t[0], t[1], t[2], t[3]);
    *(float4*)(out + base + 4) = make_float4(t[4], t[5], t[6], t[7]);
}

// ---------------------------------------------------------------------------
// Global (full, unmasked) attention, flash-style online softmax.
// 1 thread = 1 query row. Block 128 threads. Grid: (S/128, B*H).
// qkv layout (B,S,3D): q at col h*64, k at 512+h*64, v at 1024+h*64.
// ---------------------------------------------------------------------------
__global__ __launch_bounds__(128) void attn_global_kernel(
    const float* __restrict__ qkv, float* __restrict__ out)
{
    __shared__ float Ks[64][64];
    __shared__ float Vs[64][64];
    const int tid = threadIdx.x;
    const int bh = blockIdx.y;
    const int b = bh >> 3, h = bh & 7;
    const int row = blockIdx.x * 128 + tid;

    const float* qp = qkv + ((size_t)(b * S_) + row) * TRD + h * DH_;
    float q[64];
    #pragma unroll
    for (int d = 0; d < 64; d += 4) *(float4*)&q[d] = *(const float4*)(qp + d);
    float o[64];
    #pragma unroll
    for (int d = 0; d < 64; d++) o[d] = 0.f;
    float mx = -3.0e38f, l = 0.f;

    for (int kt = 0; kt < S_; kt += 64) {
        __syncthreads();
        #pragma unroll
        for (int i = 0; i < 8; i++) {
            int idx = tid + i * 128;          // 0..1023
            int j  = idx >> 4;                // key row 0..63
            int c4 = (idx & 15) << 2;         // 0..60
            const float* kp = qkv + ((size_t)(b * S_) + kt + j) * TRD + D_ + h * DH_ + c4;
            *(float4*)&Ks[j][c4] = *(const float4*)kp;
            *(float4*)&Vs[j][c4] = *(const float4*)(kp + D_);
        }
        __syncthreads();
        for (int j = 0; j < 64; j++) {
            float s = 0.f;
            #pragma unroll
            for (int d = 0; d < 64; d++) s = fmaf(q[d], Ks[j][d], s);
            s *= 0.125f;                      // DH^-0.5
            if (s > mx) {
                float corr = __expf(mx - s);  // exp(-huge)=0 on first hit
                l *= corr;
                #pragma unroll
                for (int d = 0; d < 64; d++) o[d] *= corr;
                mx = s;
            }
            float p = __expf(s - mx);
            l += p;
            #pragma unroll
            for (int d = 0; d < 64; d++) o[d] = fmaf(p, Vs[j][d], o[d]);
        }
    }
    float inv = 1.0f / l;
    float* op = out + ((size_t)(b * S_) + row) * D_ + h * DH_;
    #pragma unroll
    for (int d = 0; d < 64; d += 4)
        *(float4*)(op + d) = make_float4(o[d] * inv, o[d+1] * inv, o[d+2] * inv, o[d+3] * inv);
}

// ---------------------------------------------------------------------------
// RoPE (+0.125 scale on q) applied in place to local qkv buffer.
// 1 thread per (b,s,h,d<32) rotation pair, handles both q and k.
// ---------------------------------------------------------------------------
__global__ __launch_bounds__(256) void rope_kernel(float* __restrict__ qkv)
{
    int idx = blockIdx.x * 256 + threadIdx.x;   // < B*S*H*32
    int d  = idx & 31;
    int h  = (idx >> 5) & 7;
    int bs = idx >> 8;                          // b*S+s
    int pos = bs & (S_ - 1);
    // inv_freq = 10000^(-2d/64) = 2^(-d*(2/64)*log2(10000))
    float inv_freq = exp2f(-(float)d * (2.0f / 64.0f) * 13.287712379549449f);
    float ang = (float)pos * inv_freq;
    float sn, cs;
    sincosf(ang, &sn, &cs);
    float* base = qkv + (size_t)bs * TRD + h * DH_;
    float q1 = base[d], q2 = base[d + 32];
    base[d]      = (q1 * cs - q2 * sn) * 0.125f;   // fold in q scale
    base[d + 32] = (q2 * cs + q1 * sn) * 0.125f;
    float* kb = base + D_;
    float k1 = kb[d], k2 = kb[d + 32];
    kb[d]      = k1 * cs - k2 * sn;
    kb[d + 32] = k2 * cs + k1 * sn;
}

// ---------------------------------------------------------------------------
// Local windowed attention with look-back: window n attends keys of windows
// n-1 and n with causal mask kpos<=qpos (and kpos>=0).
// 1 thread = 1 query row; block 128 = one (b,h,window). Grid: B*H*NW.
// ---------------------------------------------------------------------------
__global__ __launch_bounds__(128) void attn_local_kernel(
    const float* __restrict__ qkv, float* __restrict__ out)
{
    __shared__ float Ks[64][64];
    __shared__ float Vs[64][64];
    const int tid = threadIdx.x;
    const int blk = blockIdx.x;
    const int n = blk & 15;
    const int h = (blk >> 4) & 7;
    const int b = blk >> 7;
    const int qpos = n * W_ + tid;

    const float* qp = qkv + ((size_t)(b * S_) + qpos) * TRD + h * DH_;
    float q[64];
    #pragma unroll
    for (int d = 0; d < 64; d += 4) *(float4*)&q[d] = *(const float4*)(qp + d);
    float o[64];
    #pragma unroll
    for (int d = 0; d < 64; d++) o[d] = 0.f;
    float mx = -3.0e38f, l = 0.f;

    for (int kt = 0; kt < 4; kt++) {
        const int kbase = n * W_ - W_ + kt * 64;   // kpos of tile key 0
        if (kbase + 63 < 0) continue;              // uniform per block: whole tile masked
        __syncthreads();
        #pragma unroll
        for (int i = 0; i < 8; i++) {
            int idx = tid + i * 128;
            int j  = idx >> 4;
            int c4 = (idx & 15) << 2;
            int kp = kbase + j; if (kp < 0) kp = 0;  // clamp (masked anyway)
            const float* kr = qkv + ((size_t)(b * S_) + kp) * TRD + D_ + h * DH_ + c4;
            *(float4*)&Ks[j][c4] = *(const float4*)kr;
            *(float4*)&Vs[j][c4] = *(const float4*)(kr + D_);
        }
        __syncthreads();
        for (int j = 0; j < 64; j++) {
            int kp = kbase + j;
            bool valid = (kp >= 0) && (kp <= qpos);
            float s = 0.f;
            #pragma unroll
            for (int d = 0; d < 64; d++) s = fmaf(q[d], Ks[j][d], s);
            s = valid ? s : -3.0e38f;          // q pre-scaled in rope_kernel
            if (s > mx) {
                float corr = __expf(mx - s);
                l *= corr;
                #pragma unroll
                for (int d = 0; d < 64; d++) o[d] *= corr;
                mx = s;
            }
            float p = valid ? __expf(s - mx) : 0.f;  // guard: all-masked tile keeps p=0
            l += p;
            #pragma unroll
            for (int d = 0; d < 64; d++) o[d] = fmaf(p, Vs[j][d], o[d]);
        }
    }
    float inv = 1.0f / l;   // diagonal key always valid -> l > 0
    float* op = out + ((size_t)(b * S_) + qpos) * D_ + h * DH_;
    #pragma unroll
    for (int d = 0; d < 64; d += 4)
        *(float4*)(op + d) = make_float4(o[d] * inv, o[d+1] * inv, o[d+2] * inv, o[d+3] * inv);
}

// ---------------------------------------------------------------------------
extern "C" void kernel_launch(void* const* d_in, const int* in_sizes, int n_in,
                              void* d_out, int out_size, void* d_ws, size_t ws_size,
                              hipStream_t stream)
{
    (void)in_sizes; (void)n_in; (void)out_size; (void)ws_size;
    const float* src        = (const float*)d_in[0];
    const float* in_proj_w  = (const float*)d_in[1];
    const float* in_proj_b  = (const float*)d_in[2];
    const float* out_proj_w = (const float*)d_in[3];
    const float* out_proj_b = (const float*)d_in[4];
    const float* ln_g       = (const float*)d_in[5];
    const float* ln_b       = (const float*)d_in[6];
    const float* qkv_w      = (const float*)d_in[7];
    const float* to_out_w   = (const float*)d_in[8];
    const float* gl_w       = (const float*)d_in[9];
    const float* gl_b       = (const float*)d_in[10];
    const float* norm1_g    = (const float*)d_in[11];
    const float* norm1_b    = (const float*)d_in[12];
    const float* lin1_w     = (const float*)d_in[13];
    const float* lin1_b     = (const float*)d_in[14];
    const float* lin2_w     = (const float*)d_in[15];
    const float* lin2_b     = (const float*)d_in[16];
    const float* norm2_g    = (const float*)d_in[17];
    const float* norm2_b    = (const float*)d_in[18];
    float* out = (float*)d_out;
    float* ws  = (float*)d_ws;

    const size_t MR = (size_t)B_ * S_;          // 8192 rows
    // Workspace layout (floats), total 29,360,128 f = 117.4 MB:
    //   buf1 [0,        4.19M)  tmp: attn_out / x / lo_pre / src2 / ff2
    //   buf3 [4.19M,    8.39M)  h1 (persists through FFN)
    //   buf0 [8.39M,   20.97M)  qkv (global, then local)
    //   buf2 [20.97M,  29.36M)  cat = [go | lo]  (B,S,2D)
    //   ff1 overlays buf0..buf2-region [8.39M, 25.17M) — both dead by step 11
    float* buf1 = ws;
    float* buf3 = buf1 + MR * D_;
    float* buf0 = buf3 + MR * D_;
    float* buf2 = buf0 + MR * TRD;
    float* ff1  = buf0;

    dim3 blk256(256), blk128(128);

    // 1. qkv_g = src @ in_proj_w^T + in_proj_b                    -> buf0
    gemm_kernel<<<dim3(TRD / 128, MR / 128), blk256, 0, stream>>>(
        src, D_, in_proj_w, in_proj_b, buf0, TRD, D_, 0);
    // 2. global flash attention                                   -> buf1
    attn_global_kernel<<<dim3(S_ / 128, B_ * H_), blk128, 0, stream>>>(buf0, buf1);
    // 3. go = attn_out @ out_proj_w^T + b                         -> cat[:, :512]
    gemm_kernel<<<dim3(D_ / 128, MR / 128), blk256, 0, stream>>>(
        buf1, D_, out_proj_w, out_proj_b, buf2, 2 * D_, D_, 0);
    // 4. x = LN(src)                                              -> buf1
    addln_kernel<<<dim3(MR / 4), blk256, 0, stream>>>(src, nullptr, ln_g, ln_b, buf1);
    // 5. qkv_l = x @ qkv_w^T (no bias)                            -> buf0
    gemm_kernel<<<dim3(TRD / 128, MR / 128), blk256, 0, stream>>>(
        buf1, D_, qkv_w, nullptr, buf0, TRD, D_, 0);
    // 6. RoPE on q,k + fold 0.125 scale into q (in place)
    rope_kernel<<<dim3((B_ * S_ * H_ * 32) / 256), blk256, 0, stream>>>(buf0);
    // 7. local windowed attention                                 -> buf1
    attn_local_kernel<<<dim3(B_ * H_ * NW_), blk128, 0, stream>>>(buf0, buf1);
    // 8. lo = lo_pre @ to_out_w^T (no bias)                       -> cat[:, 512:]
    gemm_kernel<<<dim3(D_ / 128, MR / 128), blk256, 0, stream>>>(
        buf1, D_, to_out_w, nullptr, buf2 + D_, 2 * D_, D_, 0);
    // 9. src2 = cat @ gl_w^T + gl_b   (K=1024)                    -> buf1
    gemm_kernel<<<dim3(D_ / 128, MR / 128), blk256, 0, stream>>>(
        buf2, 2 * D_, gl_w, gl_b, buf1, D_, 2 * D_, 0);
    // 10. h1 = LN(src + src2)                                     -> buf3
    addln_kernel<<<dim3(MR / 4), blk256, 0, stream>>>(src, buf1, norm1_g, norm1_b, buf3);
    // 11. ff1 = relu(h1 @ lin1_w^T + lin1_b)                      -> ff1 (overlay)
    gemm_kernel<<<dim3(FF_ / 128, MR / 128), blk256, 0, stream>>>(
        buf3, D_, lin1_w, lin1_b, ff1, FF_, D_, 1);
    // 12. ff2 = ff1 @ lin2_w^T + lin2_b   (K=2048)                -> buf1
    gemm_kernel<<<dim3(D_ / 128, MR / 128), blk256, 0, stream>>>(
        ff1, FF_, lin2_w, lin2_b, buf1, D_, FF_, 0);
    // 13. out = LN(h1 + ff2)                                      -> d_out
    addln_kernel<<<dim3(MR / 4), blk256, 0, stream>>>(buf3, buf1, norm2_g, norm2_b, out);
}

// Round 2
// 1464.217 us; speedup vs baseline: 1.7051x; 1.7051x over previous
//
#include <hip/hip_runtime.h>
#include <math.h>

#define B_  4
#define S_  2048
#define D_  512
#define H_  8
#define FF_ 2048
#define W_  128
#define DH_ 64
#define NW_ 16
#define TRD (3*D_)   // 1536

typedef __attribute__((ext_vector_type(8))) short short8;
typedef __attribute__((ext_vector_type(4))) float f32x4;

__device__ __forceinline__ short f2bf(float f) {
    unsigned u = __float_as_uint(f);
    unsigned r = (u + 0x7fff + ((u >> 16) & 1)) >> 16;   // RNE
    return (short)r;
}

// ---------------------------------------------------------------------------
// Generic fp32 GEMM: C[M,N] = A[M,K] @ W[N,K]^T (+bias) (+relu)
// ---------------------------------------------------------------------------
__global__ __launch_bounds__(256) void gemm_kernel(
    const float* __restrict__ A, int lda,
    const float* __restrict__ Wt,
    const float* __restrict__ bias,
    float* __restrict__ C, int ldc,
    int K, int relu)
{
    __shared__ float As[16][132];
    __shared__ float Ws[16][132];
    const int tid = threadIdx.x;
    const int bm = blockIdx.y * 128;
    const int bn = blockIdx.x * 128;
    const int tx = tid & 15;
    const int ty = tid >> 4;
    const int mBase = ty * 8;
    const int nBase = tx * 8;

    float acc[8][8];
    #pragma unroll
    for (int i = 0; i < 8; i++)
        #pragma unroll
        for (int j = 0; j < 8; j++) acc[i][j] = 0.f;

    for (int k0 = 0; k0 < K; k0 += 16) {
        #pragma unroll
        for (int i = 0; i < 2; i++) {
            int idx = tid + i * 256;
            int row = idx >> 2;
            int kc  = (idx & 3) << 2;
            float4 va = *(const float4*)(A + (size_t)(bm + row) * lda + (k0 + kc));
            As[kc + 0][row] = va.x; As[kc + 1][row] = va.y;
            As[kc + 2][row] = va.z; As[kc + 3][row] = va.w;
            float4 vw = *(const float4*)(Wt + (size_t)(bn + row) * K + (k0 + kc));
            Ws[kc + 0][row] = vw.x; Ws[kc + 1][row] = vw.y;
            Ws[kc + 2][row] = vw.z; Ws[kc + 3][row] = vw.w;
        }
        __syncthreads();
        #pragma unroll
        for (int kk = 0; kk < 16; kk++) {
            float a[8], b[8];
            *(float4*)&a[0] = *(const float4*)&As[kk][mBase];
            *(float4*)&a[4] = *(const float4*)&As[kk][mBase + 4];
            *(float4*)&b[0] = *(const float4*)&Ws[kk][nBase];
            *(float4*)&b[4] = *(const float4*)&Ws[kk][nBase + 4];
            #pragma unroll
            for (int i = 0; i < 8; i++)
                #pragma unroll
                for (int j = 0; j < 8; j++)
                    acc[i][j] = fmaf(a[i], b[j], acc[i][j]);
        }
        __syncthreads();
    }

    float bvals[8];
    #pragma unroll
    for (int j = 0; j < 8; j++) bvals[j] = bias ? bias[bn + nBase + j] : 0.f;
    #pragma unroll
    for (int i = 0; i < 8; i++) {
        size_t m = (size_t)(bm + mBase + i);
        float t[8];
        #pragma unroll
        for (int j = 0; j < 8; j++) {
            float v = acc[i][j] + bvals[j];
            if (relu) v = v > 0.f ? v : 0.f;
            t[j] = v;
        }
        *(float4*)(C + m * ldc + bn + nBase)     = make_float4(t[0], t[1], t[2], t[3]);
        *(float4*)(C + m * ldc + bn + nBase + 4) = make_float4(t[4], t[5], t[6], t[7]);
    }
}

// ---------------------------------------------------------------------------
// Wave(64)-per-row LayerNorm over D=512; optional second input added first.
// ---------------------------------------------------------------------------
__device__ __forceinline__ float wave_sum64(float v) {
    #pragma unroll
    for (int off = 32; off > 0; off >>= 1) v += __shfl_xor(v, off, 64);
    return v;
}

__global__ __launch_bounds__(256) void addln_kernel(
    const float* __restrict__ a, const float* __restrict__ b,
    const float* __restrict__ g, const float* __restrict__ be,
    float* __restrict__ out)
{
    const int lane = threadIdx.x & 63;
    const int row  = blockIdx.x * 4 + (threadIdx.x >> 6);
    const size_t base = (size_t)row * D_ + lane * 8;
    float v[8];
    *(float4*)&v[0] = *(const float4*)(a + base);
    *(float4*)&v[4] = *(const float4*)(a + base + 4);
    if (b) {
        float w[8];
        *(float4*)&w[0] = *(const float4*)(b + base);
        *(float4*)&w[4] = *(const float4*)(b + base + 4);
        #pragma unroll
        for (int i = 0; i < 8; i++) v[i] += w[i];
    }
    float s = 0.f;
    #pragma unroll
    for (int i = 0; i < 8; i++) s += v[i];
    float mean = wave_sum64(s) * (1.0f / 512.0f);
    float vs = 0.f;
    #pragma unroll
    for (int i = 0; i < 8; i++) { float d = v[i] - mean; vs += d * d; }
    float var = wave_sum64(vs) * (1.0f / 512.0f);
    float r = rsqrtf(var + 1e-5f);
    const int c = lane * 8;
    float t[8];
    #pragma unroll
    for (int i = 0; i < 8; i++) t[i] = (v[i] - mean) * r * g[c + i] + be[c + i];
    *(float4*)(out + base)     = make_float4(t[0], t[1], t[2], t[3]);
    *(float4*)(out + base + 4) = make_float4(t[4], t[5], t[6], t[7]);
}

// ---------------------------------------------------------------------------
// Global attention, bf16 MFMA flash. Block 256 = 4 waves; wave w owns q-rows
// [qbase + w*16, +16). K-tile 64. LDS: Ks[key][dim] pitch 72, Vt[dim][key]
// pitch 72 (transposed for PV B-fragments), P per-wave 16x72.
// MFMA 16x16x32 layouts (m89/m91/m120 verified):
//   A-frag: A[m=lane&15][k=quad*8+j], B-frag: B[n=lane&15][k=quad*8+j]
//   C/D:    row=quad*4+reg, col=lane&15
// ---------------------------------------------------------------------------
#define KP 72   // LDS row pitch (shorts): 2-way bank alias only (free), 16B-aligned

__global__ __launch_bounds__(256) void attn_global_mfma_kernel(
    const float* __restrict__ qkv, float* __restrict__ out)
{
    __shared__ short Ks[64 * KP];
    __shared__ short Vt[64 * KP];
    __shared__ short Pb[4 * 16 * KP];

    const int tid  = threadIdx.x;
    const int w    = tid >> 6;
    const int lane = tid & 63;
    const int quad = lane >> 4;
    const int x    = lane & 15;
    const int bh = blockIdx.y;
    const int b = bh >> 3, h = bh & 7;
    const int qbase = blockIdx.x * 64;
    const size_t bS = (size_t)b * S_;

    // --- Q fragments (once): q-row = qbase + w*16 + x, scale 0.125 folded in
    short8 aq[2];
    {
        const float* qp = qkv + (bS + qbase + w * 16 + x) * TRD + h * DH_;
        #pragma unroll
        for (int kc = 0; kc < 2; kc++) {
            float qv[8];
            *(float4*)&qv[0] = *(const float4*)(qp + kc * 32 + quad * 8);
            *(float4*)&qv[4] = *(const float4*)(qp + kc * 32 + quad * 8 + 4);
            #pragma unroll
            for (int j = 0; j < 8; j++) aq[kc][j] = f2bf(qv[j] * 0.125f);
        }
    }

    f32x4 o[4];
    #pragma unroll
    for (int dt = 0; dt < 4; dt++) o[dt] = (f32x4)0.f;
    float m[4], l[4];
    #pragma unroll
    for (int r = 0; r < 4; r++) { m[r] = -3.0e38f; l[r] = 0.f; }

    short* Pw = &Pb[w * 16 * KP];

    for (int kt = 0; kt < S_; kt += 64) {
        __syncthreads();   // previous iteration's LDS reads complete
        // --- stage K tile: [key][dim] bf16
        #pragma unroll
        for (int i = 0; i < 4; i++) {
            int idx = tid + i * 256;          // 1024 float4 slots
            int j   = idx >> 4;               // key 0..63
            int c4  = (idx & 15) << 2;        // dim 0..60
            float4 kv = *(const float4*)(qkv + (bS + kt + j) * TRD + D_ + h * DH_ + c4);
            short* d = &Ks[j * KP + c4];
            d[0] = f2bf(kv.x); d[1] = f2bf(kv.y); d[2] = f2bf(kv.z); d[3] = f2bf(kv.w);
        }
        // --- stage V tile transposed: Vt[dim][key]
        {
            int d  = tid & 63;
            int jb = (tid >> 6) * 16;
            const float* vp = qkv + (bS + kt + jb) * TRD + 2 * D_ + h * DH_ + d;
            short8 s0, s1;
            #pragma unroll
            for (int jj = 0; jj < 8; jj++) s0[jj] = f2bf(vp[(size_t)jj * TRD]);
            #pragma unroll
            for (int jj = 0; jj < 8; jj++) s1[jj] = f2bf(vp[(size_t)(jj + 8) * TRD]);
            *(short8*)&Vt[d * KP + jb]     = s0;
            *(short8*)&Vt[d * KP + jb + 8] = s1;
        }
        __syncthreads();

        // --- S = Q K^T : 4 n-tiles of 16 keys
        f32x4 sc[4];
        #pragma unroll
        for (int nt = 0; nt < 4; nt++) {
            sc[nt] = (f32x4)0.f;
            #pragma unroll
            for (int kc = 0; kc < 2; kc++) {
                short8 bk = *(const short8*)&Ks[(nt * 16 + x) * KP + kc * 32 + quad * 8];
                sc[nt] = __builtin_amdgcn_mfma_f32_16x16x32_bf16(aq[kc], bk, sc[nt], 0, 0, 0);
            }
        }

        // --- online softmax (rows = quad*4+r, cols across 16 lanes x 4 nt)
        #pragma unroll
        for (int r = 0; r < 4; r++) {
            float mx = fmaxf(fmaxf(sc[0][r], sc[1][r]), fmaxf(sc[2][r], sc[3][r]));
            #pragma unroll
            for (int off = 1; off < 16; off <<= 1) mx = fmaxf(mx, __shfl_xor(mx, off, 64));
            float mnew = fmaxf(m[r], mx);
            float alpha = __expf(m[r] - mnew);
            m[r] = mnew;
            float psum = 0.f;
            #pragma unroll
            for (int nt = 0; nt < 4; nt++) {
                float p = __expf(sc[nt][r] - mnew);
                sc[nt][r] = p;
                psum += p;
            }
            #pragma unroll
            for (int off = 1; off < 16; off <<= 1) psum += __shfl_xor(psum, off, 64);
            l[r] = l[r] * alpha + psum;
            #pragma unroll
            for (int dt = 0; dt < 4; dt++) o[dt][r] *= alpha;
            // write P row (C-layout position)
            #pragma unroll
            for (int nt = 0; nt < 4; nt++)
                Pw[(quad * 4 + r) * KP + nt * 16 + x] = f2bf(sc[nt][r]);
        }
        asm volatile("s_waitcnt lgkmcnt(0)" ::: "memory");  // own-wave P writes visible

        // --- O += P V : A-frag from Pw, B-frag from Vt
        #pragma unroll
        for (int kc = 0; kc < 2; kc++) {
            short8 ap = *(const short8*)&Pw[x * KP + kc * 32 + quad * 8];
            #pragma unroll
            for (int dt = 0; dt < 4; dt++) {
                short8 bv = *(const short8*)&Vt[(dt * 16 + x) * KP + kc * 32 + quad * 8];
                o[dt] = __builtin_amdgcn_mfma_f32_16x16x32_bf16(ap, bv, o[dt], 0, 0, 0);
            }
        }
    }

    // --- epilogue: O /= l, store (row=quad*4+r, col=dt*16+x)
    #pragma unroll
    for (int r = 0; r < 4; r++) {
        float inv = 1.0f / l[r];
        size_t rowbase = (bS + qbase + w * 16 + quad * 4 + r) * D_ + h * DH_;
        #pragma unroll
        for (int dt = 0; dt < 4; dt++)
            out[rowbase + dt * 16 + x] = o[dt][r] * inv;
    }
}

// ---------------------------------------------------------------------------
// RoPE (+0.125 scale on q) applied in place to local qkv buffer.
// ---------------------------------------------------------------------------
__global__ __launch_bounds__(256) void rope_kernel(float* __restrict__ qkv)
{
    int idx = blockIdx.x * 256 + threadIdx.x;
    int d  = idx & 31;
    int h  = (idx >> 5) & 7;
    int bs = idx >> 8;
    int pos = bs & (S_ - 1);
    float inv_freq = exp2f(-(float)d * (2.0f / 64.0f) * 13.287712379549449f);
    float ang = (float)pos * inv_freq;
    float sn, cs;
    sincosf(ang, &sn, &cs);
    float* base = qkv + (size_t)bs * TRD + h * DH_;
    float q1 = base[d], q2 = base[d + 32];
    base[d]      = (q1 * cs - q2 * sn) * 0.125f;
    base[d + 32] = (q2 * cs + q1 * sn) * 0.125f;
    float* kb = base + D_;
    float k1 = kb[d], k2 = kb[d + 32];
    kb[d]      = k1 * cs - k2 * sn;
    kb[d + 32] = k2 * cs + k1 * sn;
}

// ---------------------------------------------------------------------------
// Local windowed attention (fp32, 1 thread = 1 query row).
// ---------------------------------------------------------------------------
__global__ __launch_bounds__(128) void attn_local_kernel(
    const float* __restrict__ qkv, float* __restrict__ out)
{
    __shared__ float Ks[64][64];
    __shared__ float Vs[64][64];
    const int tid = threadIdx.x;
    const int blk = blockIdx.x;
    const int n = blk & 15;
    const int h = (blk >> 4) & 7;
    const int b = blk >> 7;
    const int qpos = n * W_ + tid;

    const float* qp = qkv + ((size_t)(b * S_) + qpos) * TRD + h * DH_;
    float q[64];
    #pragma unroll
    for (int d = 0; d < 64; d += 4) *(float4*)&q[d] = *(const float4*)(qp + d);
    float o[64];
    #pragma unroll
    for (int d = 0; d < 64; d++) o[d] = 0.f;
    float mx = -3.0e38f, l = 0.f;

    for (int kt = 0; kt < 4; kt++) {
        const int kbase = n * W_ - W_ + kt * 64;
        if (kbase + 63 < 0) continue;
        __syncthreads();
        #pragma unroll
        for (int i = 0; i < 8; i++) {
            int idx = tid + i * 128;
            int j  = idx >> 4;
            int c4 = (idx & 15) << 2;
            int kp = kbase + j; if (kp < 0) kp = 0;
            const float* kr = qkv + ((size_t)(b * S_) + kp) * TRD + D_ + h * DH_ + c4;
            *(float4*)&Ks[j][c4] = *(const float4*)kr;
            *(float4*)&Vs[j][c4] = *(const float4*)(kr + D_);
        }
        __syncthreads();
        for (int j = 0; j < 64; j++) {
            int kp = kbase + j;
            bool valid = (kp >= 0) && (kp <= qpos);
            float s = 0.f;
            #pragma unroll
            for (int d = 0; d < 64; d++) s = fmaf(q[d], Ks[j][d], s);
            s = valid ? s : -3.0e38f;
            if (s > mx) {
                float corr = __expf(mx - s);
                l *= corr;
                #pragma unroll
                for (int d = 0; d < 64; d++) o[d] *= corr;
                mx = s;
            }
            float p = valid ? __expf(s - mx) : 0.f;
            l += p;
            #pragma unroll
            for (int d = 0; d < 64; d++) o[d] = fmaf(p, Vs[j][d], o[d]);
        }
    }
    float inv = 1.0f / l;
    float* op = out + ((size_t)(b * S_) + qpos) * D_ + h * DH_;
    #pragma unroll
    for (int d = 0; d < 64; d += 4)
        *(float4*)(op + d) = make_float4(o[d] * inv, o[d+1] * inv, o[d+2] * inv, o[d+3] * inv);
}

// ---------------------------------------------------------------------------
extern "C" void kernel_launch(void* const* d_in, const int* in_sizes, int n_in,
                              void* d_out, int out_size, void* d_ws, size_t ws_size,
                              hipStream_t stream)
{
    (void)in_sizes; (void)n_in; (void)out_size; (void)ws_size;
    const float* src        = (const float*)d_in[0];
    const float* in_proj_w  = (const float*)d_in[1];
    const float* in_proj_b  = (const float*)d_in[2];
    const float* out_proj_w = (const float*)d_in[3];
    const float* out_proj_b = (const float*)d_in[4];
    const float* ln_g       = (const float*)d_in[5];
    const float* ln_b       = (const float*)d_in[6];
    const float* qkv_w      = (const float*)d_in[7];
    const float* to_out_w   = (const float*)d_in[8];
    const float* gl_w       = (const float*)d_in[9];
    const float* gl_b       = (const float*)d_in[10];
    const float* norm1_g    = (const float*)d_in[11];
    const float* norm1_b    = (const float*)d_in[12];
    const float* lin1_w     = (const float*)d_in[13];
    const float* lin1_b     = (const float*)d_in[14];
    const float* lin2_w     = (const float*)d_in[15];
    const float* lin2_b     = (const float*)d_in[16];
    const float* norm2_g    = (const float*)d_in[17];
    const float* norm2_b    = (const float*)d_in[18];
    float* out = (float*)d_out;
    float* ws  = (float*)d_ws;

    const size_t MR = (size_t)B_ * S_;          // 8192 rows
    float* buf1 = ws;
    float* buf3 = buf1 + MR * D_;
    float* buf0 = buf3 + MR * D_;
    float* buf2 = buf0 + MR * TRD;
    float* ff1  = buf0;

    dim3 blk256(256), blk128(128);

    // 1. qkv_g = src @ in_proj_w^T + in_proj_b                    -> buf0
    gemm_kernel<<<dim3(TRD / 128, MR / 128), blk256, 0, stream>>>(
        src, D_, in_proj_w, in_proj_b, buf0, TRD, D_, 0);
    // 2. global flash attention (bf16 MFMA)                       -> buf1
    attn_global_mfma_kernel<<<dim3(S_ / 64, B_ * H_), blk256, 0, stream>>>(buf0, buf1);
    // 3. go = attn_out @ out_proj_w^T + b                         -> cat[:, :512]
    gemm_kernel<<<dim3(D_ / 128, MR / 128), blk256, 0, stream>>>(
        buf1, D_, out_proj_w, out_proj_b, buf2, 2 * D_, D_, 0);
    // 4. x = LN(src)                                              -> buf1
    addln_kernel<<<dim3(MR / 4), blk256, 0, stream>>>(src, nullptr, ln_g, ln_b, buf1);
    // 5. qkv_l = x @ qkv_w^T (no bias)                            -> buf0
    gemm_kernel<<<dim3(TRD / 128, MR / 128), blk256, 0, stream>>>(
        buf1, D_, qkv_w, nullptr, buf0, TRD, D_, 0);
    // 6. RoPE on q,k + fold 0.125 scale into q (in place)
    rope_kernel<<<dim3((B_ * S_ * H_ * 32) / 256), blk256, 0, stream>>>(buf0);
    // 7. local windowed attention                                 -> buf1
    attn_local_kernel<<<dim3(B_ * H_ * NW_), blk128, 0, stream>>>(buf0, buf1);
    // 8. lo = lo_pre @ to_out_w^T (no bias)                       -> cat[:, 512:]
    gemm_kernel<<<dim3(D_ / 128, MR / 128), blk256, 0, stream>>>(
        buf1, D_, to_out_w, nullptr, buf2 + D_, 2 * D_, D_, 0);
    // 9. src2 = cat @ gl_w^T + gl_b   (K=1024)                    -> buf1
    gemm_kernel<<<dim3(D_ / 128, MR / 128), blk256, 0, stream>>>(
        buf2, 2 * D_, gl_w, gl_b, buf1, D_, 2 * D_, 0);
    // 10. h1 = LN(src + src2)                                     -> buf3
    addln_kernel<<<dim3(MR / 4), blk256, 0, stream>>>(src, buf1, norm1_g, norm1_b, buf3);
    // 11. ff1 = relu(h1 @ lin1_w^T + lin1_b)                      -> ff1 (overlay)
    gemm_kernel<<<dim3(FF_ / 128, MR / 128), blk256, 0, stream>>>(
        buf3, D_, lin1_w, lin1_b, ff1, FF_, D_, 1);
    // 12. ff2 = ff1 @ lin2_w^T + lin2_b   (K=2048)                -> buf1
    gemm_kernel<<<dim3(D_ / 128, MR / 128), blk256, 0, stream>>>(
        ff1, FF_, lin2_w, lin2_b, buf1, D_, FF_, 0);
    // 13. out = LN(h1 + ff2)                                      -> d_out
    addln_kernel<<<dim3(MR / 4), blk256, 0, stream>>>(buf3, buf1, norm2_g, norm2_b, out);
}

// Round 3
// 560.808 us; speedup vs baseline: 4.4519x; 2.6109x over previous
//
#include <hip/hip_runtime.h>
#include <math.h>

#define B_  4
#define S_  2048
#define D_  512
#define H_  8
#define FF_ 2048
#define W_  128
#define DH_ 64
#define NW_ 16
#define TRD (3*D_)   // 1536
#define MR_ (B_*S_)  // 8192 rows

typedef __attribute__((ext_vector_type(8))) short short8;
typedef __attribute__((ext_vector_type(4))) float f32x4;

__device__ __forceinline__ short f2bf(float f) {
    unsigned u = __float_as_uint(f);
    unsigned r = (u + 0x7fff + ((u >> 16) & 1)) >> 16;   // RNE
    return (short)r;
}
__device__ __forceinline__ float bf2f(ushort u) {
    return __uint_as_float(((unsigned)u) << 16);
}
__device__ __forceinline__ void gload_lds16(const ushort* g, short* l) {
    __builtin_amdgcn_global_load_lds(
        (const __attribute__((address_space(1))) void*)g,
        (__attribute__((address_space(3))) void*)l, 16, 0, 0);
}

// ---------------------------------------------------------------------------
// Fused fp32 -> bf16 conversion for src + 7 weight tensors.
// ---------------------------------------------------------------------------
struct CvtJobs { const float* s[8]; ushort* d[8]; int n[8]; };

__global__ __launch_bounds__(256) void cvt_kernel(CvtJobs jobs)
{
    int i4 = (blockIdx.x * 256 + threadIdx.x) * 4;
    #pragma unroll
    for (int j = 0; j < 8; j++) {
        if (i4 < jobs.n[j]) {
            float4 v = *(const float4*)(jobs.s[j] + i4);
            ushort4 o;
            o.x = (ushort)f2bf(v.x); o.y = (ushort)f2bf(v.y);
            o.z = (ushort)f2bf(v.z); o.w = (ushort)f2bf(v.w);
            *(ushort4*)(jobs.d[j] + i4) = o;
        }
    }
}

// ---------------------------------------------------------------------------
// bf16 MFMA GEMM (m97 recipe): C[M,N] = A[M,K] @ W[N,K]^T (+bias fp32)(+relu)
// 128x128 tile, BK=64. Block 256 = 4 waves in 2x2; each wave 64x64 = 4x4
// MFMA 16x16x32 tiles. A,W staged via global_load_lds width 16 (LDS layout
// row-major pitch 64 shorts, no pad -- required by lane-ordered DMA).
// Verified fragment layouts (m89/m91): A[m=x][k=quad*8+j], B[n=x][k=quad*8+j],
// C/D row=quad*4+r, col=x.
// ---------------------------------------------------------------------------
__global__ __launch_bounds__(256) void gemm_bf16_kernel(
    const ushort* __restrict__ A, int lda,
    const ushort* __restrict__ Wt,     // [N][K] row-major
    const float* __restrict__ bias,
    ushort* __restrict__ C, int ldc,
    int K, int relu)
{
    __shared__ short As[128 * 64];
    __shared__ short Bs[128 * 64];
    const int tid  = threadIdx.x;
    const int w    = tid >> 6;
    const int lane = tid & 63;
    const int quad = lane >> 4;
    const int x    = lane & 15;
    const int wr = w >> 1, wc = w & 1;
    const int bm = blockIdx.y * 128;
    const int bn = blockIdx.x * 128;

    // staging map: wave w stages rows [w*32, w*32+32), chunk c = 8 rows;
    // lane l -> row +l/8, col (l&7)*8   (matches DMA lane*16B ordering)
    const int srow = w * 32 + (lane >> 3);
    const int scol = (lane & 7) * 8;

    f32x4 acc[4][4];
    #pragma unroll
    for (int i = 0; i < 4; i++)
        #pragma unroll
        for (int j = 0; j < 4; j++) acc[i][j] = (f32x4)0.f;

    for (int k0 = 0; k0 < K; k0 += 64) {
        __syncthreads();   // prior fragment reads done before overwrite
        #pragma unroll
        for (int c = 0; c < 4; c++) {
            const ushort* ga = A + (size_t)(bm + srow + c * 8) * lda + k0 + scol;
            gload_lds16(ga, &As[(w * 32 + c * 8) * 64]);
            const ushort* gb = Wt + (size_t)(bn + srow + c * 8) * K + k0 + scol;
            gload_lds16(gb, &Bs[(w * 32 + c * 8) * 64]);
        }
        __syncthreads();   // drains vmcnt -> LDS writes visible

        #pragma unroll
        for (int kc = 0; kc < 2; kc++) {
            short8 af[4], bf[4];
            #pragma unroll
            for (int i = 0; i < 4; i++)
                af[i] = *(const short8*)&As[(wr * 64 + i * 16 + x) * 64 + kc * 32 + quad * 8];
            #pragma unroll
            for (int j = 0; j < 4; j++)
                bf[j] = *(const short8*)&Bs[(wc * 64 + j * 16 + x) * 64 + kc * 32 + quad * 8];
            #pragma unroll
            for (int i = 0; i < 4; i++)
                #pragma unroll
                for (int j = 0; j < 4; j++)
                    acc[i][j] = __builtin_amdgcn_mfma_f32_16x16x32_bf16(af[i], bf[j], acc[i][j], 0, 0, 0);
        }
    }

    #pragma unroll
    for (int i = 0; i < 4; i++) {
        #pragma unroll
        for (int r = 0; r < 4; r++) {
            size_t row = (size_t)(bm + wr * 64 + i * 16 + quad * 4 + r);
            #pragma unroll
            for (int j = 0; j < 4; j++) {
                int col = bn + wc * 64 + j * 16 + x;
                float v = acc[i][j][r] + (bias ? bias[col] : 0.f);
                if (relu) v = v > 0.f ? v : 0.f;
                C[row * ldc + col] = (ushort)f2bf(v);
            }
        }
    }
}

// ---------------------------------------------------------------------------
// LayerNorm over D=512, wave per row; templated input/output dtypes.
// ---------------------------------------------------------------------------
__device__ __forceinline__ float wave_sum64(float v) {
    #pragma unroll
    for (int off = 32; off > 0; off >>= 1) v += __shfl_xor(v, off, 64);
    return v;
}
__device__ __forceinline__ void load8(const float* p, float* v) {
    *(float4*)&v[0] = *(const float4*)p;
    *(float4*)&v[4] = *(const float4*)(p + 4);
}
__device__ __forceinline__ void load8(const ushort* p, float* v) {
    short8 s = *(const short8*)p;
    #pragma unroll
    for (int i = 0; i < 8; i++) v[i] = bf2f((ushort)s[i]);
}
__device__ __forceinline__ void store8(float* p, const float* v) {
    *(float4*)p       = make_float4(v[0], v[1], v[2], v[3]);
    *(float4*)(p + 4) = make_float4(v[4], v[5], v[6], v[7]);
}
__device__ __forceinline__ void store8(ushort* p, const float* v) {
    short8 s;
    #pragma unroll
    for (int i = 0; i < 8; i++) s[i] = f2bf(v[i]);
    *(short8*)p = s;
}

template <typename TA, typename TB, typename TO>
__global__ __launch_bounds__(256) void addln_kernel(
    const TA* __restrict__ a, const TB* __restrict__ b,
    const float* __restrict__ g, const float* __restrict__ be,
    TO* __restrict__ out)
{
    const int lane = threadIdx.x & 63;
    const int row  = blockIdx.x * 4 + (threadIdx.x >> 6);
    const size_t base = (size_t)row * D_ + lane * 8;
    float v[8];
    load8(a + base, v);
    if (b) {
        float wv[8];
        load8(b + base, wv);
        #pragma unroll
        for (int i = 0; i < 8; i++) v[i] += wv[i];
    }
    float s = 0.f;
    #pragma unroll
    for (int i = 0; i < 8; i++) s += v[i];
    float mean = wave_sum64(s) * (1.0f / 512.0f);
    float vs = 0.f;
    #pragma unroll
    for (int i = 0; i < 8; i++) { float d = v[i] - mean; vs += d * d; }
    float var = wave_sum64(vs) * (1.0f / 512.0f);
    float r = rsqrtf(var + 1e-5f);
    const int c = lane * 8;
    float t[8];
    #pragma unroll
    for (int i = 0; i < 8; i++) t[i] = (v[i] - mean) * r * g[c + i] + be[c + i];
    store8(out + base, t);
}

// ---------------------------------------------------------------------------
// Global attention, bf16 MFMA flash (layouts verified in R1).
// ---------------------------------------------------------------------------
#define KP 72   // padded pitch for Vt/Pb (144B = 16B-aligned rows, 2-way alias free)

__global__ __launch_bounds__(256) void attn_global_mfma_kernel(
    const ushort* __restrict__ qkv, ushort* __restrict__ out)
{
    __shared__ short Ks[64 * 64];     // DMA-staged, pitch 64 (no pad allowed)
    __shared__ short Vt[64 * KP];     // transposed [dim][key]
    __shared__ short Pb[4 * 16 * KP];

    const int tid  = threadIdx.x;
    const int w    = tid >> 6;
    const int lane = tid & 63;
    const int quad = lane >> 4;
    const int x    = lane & 15;
    const int bh = blockIdx.y;
    const int b = bh >> 3, h = bh & 7;
    const int qbase = blockIdx.x * 64;
    const size_t bS = (size_t)b * S_;

    short8 aq[2];
    {
        const ushort* qp = qkv + (bS + qbase + w * 16 + x) * TRD + h * DH_;
        #pragma unroll
        for (int kc = 0; kc < 2; kc++) {
            short8 raw = *(const short8*)(qp + kc * 32 + quad * 8);
            #pragma unroll
            for (int j = 0; j < 8; j++)
                aq[kc][j] = f2bf(bf2f((ushort)raw[j]) * 0.125f);
        }
    }

    f32x4 o[4];
    #pragma unroll
    for (int dt = 0; dt < 4; dt++) o[dt] = (f32x4)0.f;
    float m[4], l[4];
    #pragma unroll
    for (int r = 0; r < 4; r++) { m[r] = -3.0e38f; l[r] = 0.f; }

    short* Pw = &Pb[w * 16 * KP];

    for (int kt = 0; kt < S_; kt += 64) {
        __syncthreads();
        // K tile: rows of 64 keys x 64 dims (128B) via global_load_lds
        #pragma unroll
        for (int c = 0; c < 2; c++) {
            int key = w * 16 + c * 8 + (lane >> 3);
            const ushort* gk = qkv + (bS + kt + key) * TRD + D_ + h * DH_ + (lane & 7) * 8;
            gload_lds16(gk, &Ks[(w * 16 + c * 8) * 64]);
        }
        // V tile transposed (VALU staging)
        {
            int d  = tid & 63;
            int jb = (tid >> 6) * 16;
            const ushort* vp = qkv + (bS + kt + jb) * TRD + 2 * D_ + h * DH_ + d;
            short8 s0, s1;
            #pragma unroll
            for (int jj = 0; jj < 8; jj++) s0[jj] = (short)vp[(size_t)jj * TRD];
            #pragma unroll
            for (int jj = 0; jj < 8; jj++) s1[jj] = (short)vp[(size_t)(jj + 8) * TRD];
            *(short8*)&Vt[d * KP + jb]     = s0;
            *(short8*)&Vt[d * KP + jb + 8] = s1;
        }
        __syncthreads();

        f32x4 sc[4];
        #pragma unroll
        for (int nt = 0; nt < 4; nt++) {
            sc[nt] = (f32x4)0.f;
            #pragma unroll
            for (int kc = 0; kc < 2; kc++) {
                short8 bk = *(const short8*)&Ks[(nt * 16 + x) * 64 + kc * 32 + quad * 8];
                sc[nt] = __builtin_amdgcn_mfma_f32_16x16x32_bf16(aq[kc], bk, sc[nt], 0, 0, 0);
            }
        }

        #pragma unroll
        for (int r = 0; r < 4; r++) {
            float mx = fmaxf(fmaxf(sc[0][r], sc[1][r]), fmaxf(sc[2][r], sc[3][r]));
            #pragma unroll
            for (int off = 1; off < 16; off <<= 1) mx = fmaxf(mx, __shfl_xor(mx, off, 64));
            float mnew = fmaxf(m[r], mx);
            float alpha = __expf(m[r] - mnew);
            m[r] = mnew;
            float psum = 0.f;
            #pragma unroll
            for (int nt = 0; nt < 4; nt++) {
                float p = __expf(sc[nt][r] - mnew);
                sc[nt][r] = p;
                psum += p;
            }
            #pragma unroll
            for (int off = 1; off < 16; off <<= 1) psum += __shfl_xor(psum, off, 64);
            l[r] = l[r] * alpha + psum;
            #pragma unroll
            for (int dt = 0; dt < 4; dt++) o[dt][r] *= alpha;
            #pragma unroll
            for (int nt = 0; nt < 4; nt++)
                Pw[(quad * 4 + r) * KP + nt * 16 + x] = f2bf(sc[nt][r]);
        }
        asm volatile("s_waitcnt lgkmcnt(0)" ::: "memory");

        #pragma unroll
        for (int kc = 0; kc < 2; kc++) {
            short8 ap = *(const short8*)&Pw[x * KP + kc * 32 + quad * 8];
            #pragma unroll
            for (int dt = 0; dt < 4; dt++) {
                short8 bv = *(const short8*)&Vt[(dt * 16 + x) * KP + kc * 32 + quad * 8];
                o[dt] = __builtin_amdgcn_mfma_f32_16x16x32_bf16(ap, bv, o[dt], 0, 0, 0);
            }
        }
    }

    #pragma unroll
    for (int r = 0; r < 4; r++) {
        float inv = 1.0f / l[r];
        size_t rowbase = (bS + qbase + w * 16 + quad * 4 + r) * D_ + h * DH_;
        #pragma unroll
        for (int dt = 0; dt < 4; dt++)
            out[rowbase + dt * 16 + x] = (ushort)f2bf(o[dt][r] * inv);
    }
}

// ---------------------------------------------------------------------------
// RoPE (+0.125 on q) in place on bf16 local qkv.
// ---------------------------------------------------------------------------
__global__ __launch_bounds__(256) void rope_kernel(ushort* __restrict__ qkv)
{
    int idx = blockIdx.x * 256 + threadIdx.x;
    int d  = idx & 31;
    int h  = (idx >> 5) & 7;
    int bs = idx >> 8;
    int pos = bs & (S_ - 1);
    float inv_freq = exp2f(-(float)d * (2.0f / 64.0f) * 13.287712379549449f);
    float ang = (float)pos * inv_freq;
    float sn, cs;
    sincosf(ang, &sn, &cs);
    ushort* base = qkv + (size_t)bs * TRD + h * DH_;
    float q1 = bf2f(base[d]), q2 = bf2f(base[d + 32]);
    base[d]      = (ushort)f2bf((q1 * cs - q2 * sn) * 0.125f);
    base[d + 32] = (ushort)f2bf((q2 * cs + q1 * sn) * 0.125f);
    ushort* kb = base + D_;
    float k1 = bf2f(kb[d]), k2 = bf2f(kb[d + 32]);
    kb[d]      = (ushort)f2bf(k1 * cs - k2 * sn);
    kb[d + 32] = (ushort)f2bf(k2 * cs + k1 * sn);
}

// ---------------------------------------------------------------------------
// Local windowed attention, bf16 MFMA flash. Same structure as global;
// window n = qbase/128 attends key tiles kbase = n*128-128 + kt*64 (skip <0)
// with causal mask kpos <= qpos applied at C-layout positions.
// ---------------------------------------------------------------------------
__global__ __launch_bounds__(256) void attn_local_mfma_kernel(
    const ushort* __restrict__ qkv, ushort* __restrict__ out)
{
    __shared__ short Ks[64 * 64];
    __shared__ short Vt[64 * KP];
    __shared__ short Pb[4 * 16 * KP];

    const int tid  = threadIdx.x;
    const int w    = tid >> 6;
    const int lane = tid & 63;
    const int quad = lane >> 4;
    const int x    = lane & 15;
    const int bh = blockIdx.y;
    const int b = bh >> 3, h = bh & 7;
    const int qbase = blockIdx.x * 64;
    const int n = qbase >> 7;          // 128-window index
    const size_t bS = (size_t)b * S_;

    short8 aq[2];
    {
        const ushort* qp = qkv + (bS + qbase + w * 16 + x) * TRD + h * DH_;
        #pragma unroll
        for (int kc = 0; kc < 2; kc++)
            aq[kc] = *(const short8*)(qp + kc * 32 + quad * 8);
    }

    f32x4 o[4];
    #pragma unroll
    for (int dt = 0; dt < 4; dt++) o[dt] = (f32x4)0.f;
    float m[4], l[4];
    #pragma unroll
    for (int r = 0; r < 4; r++) { m[r] = -3.0e38f; l[r] = 0.f; }

    short* Pw = &Pb[w * 16 * KP];

    for (int kt = 0; kt < 4; kt++) {
        const int kbase = n * 128 - 128 + kt * 64;
        if (kbase < 0) continue;       // uniform per block
        __syncthreads();
        #pragma unroll
        for (int c = 0; c < 2; c++) {
            int key = w * 16 + c * 8 + (lane >> 3);
            const ushort* gk = qkv + (bS + kbase + key) * TRD + D_ + h * DH_ + (lane & 7) * 8;
            gload_lds16(gk, &Ks[(w * 16 + c * 8) * 64]);
        }
        {
            int d  = tid & 63;
            int jb = (tid >> 6) * 16;
            const ushort* vp = qkv + (bS + kbase + jb) * TRD + 2 * D_ + h * DH_ + d;
            short8 s0, s1;
            #pragma unroll
            for (int jj = 0; jj < 8; jj++) s0[jj] = (short)vp[(size_t)jj * TRD];
            #pragma unroll
            for (int jj = 0; jj < 8; jj++) s1[jj] = (short)vp[(size_t)(jj + 8) * TRD];
            *(short8*)&Vt[d * KP + jb]     = s0;
            *(short8*)&Vt[d * KP + jb + 8] = s1;
        }
        __syncthreads();

        f32x4 sc[4];
        #pragma unroll
        for (int nt = 0; nt < 4; nt++) {
            sc[nt] = (f32x4)0.f;
            #pragma unroll
            for (int kc = 0; kc < 2; kc++) {
                short8 bk = *(const short8*)&Ks[(nt * 16 + x) * 64 + kc * 32 + quad * 8];
                sc[nt] = __builtin_amdgcn_mfma_f32_16x16x32_bf16(aq[kc], bk, sc[nt], 0, 0, 0);
            }
        }
        // causal mask at C-layout: row q = qbase + w*16 + quad*4 + r, col k = kbase + nt*16 + x
        #pragma unroll
        for (int nt = 0; nt < 4; nt++) {
            int kp = kbase + nt * 16 + x;
            #pragma unroll
            for (int r = 0; r < 4; r++) {
                int qp = qbase + w * 16 + quad * 4 + r;
                if (kp > qp) sc[nt][r] = -3.0e38f;
            }
        }

        #pragma unroll
        for (int r = 0; r < 4; r++) {
            float mx = fmaxf(fmaxf(sc[0][r], sc[1][r]), fmaxf(sc[2][r], sc[3][r]));
            #pragma unroll
            for (int off = 1; off < 16; off <<= 1) mx = fmaxf(mx, __shfl_xor(mx, off, 64));
            float mnew = fmaxf(m[r], mx);
            float alpha = __expf(m[r] - mnew);
            m[r] = mnew;
            float psum = 0.f;
            #pragma unroll
            for (int nt = 0; nt < 4; nt++) {
                float p = __expf(sc[nt][r] - mnew);
                sc[nt][r] = p;
                psum += p;
            }
            #pragma unroll
            for (int off = 1; off < 16; off <<= 1) psum += __shfl_xor(psum, off, 64);
            l[r] = l[r] * alpha + psum;
            #pragma unroll
            for (int dt = 0; dt < 4; dt++) o[dt][r] *= alpha;
            #pragma unroll
            for (int nt = 0; nt < 4; nt++)
                Pw[(quad * 4 + r) * KP + nt * 16 + x] = f2bf(sc[nt][r]);
        }
        asm volatile("s_waitcnt lgkmcnt(0)" ::: "memory");

        #pragma unroll
        for (int kc = 0; kc < 2; kc++) {
            short8 ap = *(const short8*)&Pw[x * KP + kc * 32 + quad * 8];
            #pragma unroll
            for (int dt = 0; dt < 4; dt++) {
                short8 bv = *(const short8*)&Vt[(dt * 16 + x) * KP + kc * 32 + quad * 8];
                o[dt] = __builtin_amdgcn_mfma_f32_16x16x32_bf16(ap, bv, o[dt], 0, 0, 0);
            }
        }
    }

    #pragma unroll
    for (int r = 0; r < 4; r++) {
        float inv = 1.0f / l[r];
        size_t rowbase = (bS + qbase + w * 16 + quad * 4 + r) * D_ + h * DH_;
        #pragma unroll
        for (int dt = 0; dt < 4; dt++)
            out[rowbase + dt * 16 + x] = (ushort)f2bf(o[dt][r] * inv);
    }
}

// ---------------------------------------------------------------------------
extern "C" void kernel_launch(void* const* d_in, const int* in_sizes, int n_in,
                              void* d_out, int out_size, void* d_ws, size_t ws_size,
                              hipStream_t stream)
{
    (void)in_sizes; (void)n_in; (void)out_size; (void)ws_size;
    const float* src        = (const float*)d_in[0];
    const float* in_proj_w  = (const float*)d_in[1];
    const float* in_proj_b  = (const float*)d_in[2];
    const float* out_proj_w = (const float*)d_in[3];
    const float* out_proj_b = (const float*)d_in[4];
    const float* ln_g       = (const float*)d_in[5];
    const float* ln_b       = (const float*)d_in[6];
    const float* qkv_w      = (const float*)d_in[7];
    const float* to_out_w   = (const float*)d_in[8];
    const float* gl_w       = (const float*)d_in[9];
    const float* gl_b       = (const float*)d_in[10];
    const float* norm1_g    = (const float*)d_in[11];
    const float* norm1_b    = (const float*)d_in[12];
    const float* lin1_w     = (const float*)d_in[13];
    const float* lin1_b     = (const float*)d_in[14];
    const float* lin2_w     = (const float*)d_in[15];
    const float* lin2_b     = (const float*)d_in[16];
    const float* norm2_g    = (const float*)d_in[17];
    const float* norm2_b    = (const float*)d_in[18];
    float* out = (float*)d_out;

    // --- bf16 workspace layout (ushorts), total ~76.5 MB ---
    ushort* ws16   = (ushort*)d_ws;
    ushort* src_bf = ws16;                          // 8192*512
    ushort* wi_bf  = src_bf + (size_t)MR_ * D_;     // 1536*512
    ushort* wq_bf  = wi_bf  + TRD * D_;             // 1536*512
    ushort* wo_bf  = wq_bf  + TRD * D_;             // 512*512
    ushort* wt_bf  = wo_bf  + D_ * D_;              // 512*512
    ushort* wg_bf  = wt_bf  + D_ * D_;              // 512*1024
    ushort* w1_bf  = wg_bf  + D_ * 2 * D_;          // 2048*512
    ushort* w2_bf  = w1_bf  + FF_ * D_;             // 512*2048
    ushort* buf1   = w2_bf  + D_ * FF_;             // 8192*512  (attn/x/lo/src2/ff2)
    ushort* h1b    = buf1   + (size_t)MR_ * D_;     // 8192*512
    ushort* buf0   = h1b    + (size_t)MR_ * D_;     // 8192*1536 (qkv)
    ushort* buf2   = buf0   + (size_t)MR_ * TRD;    // 8192*1024 (cat)
    ushort* ff1    = buf0;                          // 8192*2048 overlays buf0+buf2

    dim3 blk256(256);

    // 0. fp32 -> bf16 conversions (src + 7 weights), one fused launch
    CvtJobs jobs;
    jobs.s[0] = src;        jobs.d[0] = src_bf; jobs.n[0] = MR_ * D_;
    jobs.s[1] = in_proj_w;  jobs.d[1] = wi_bf;  jobs.n[1] = TRD * D_;
    jobs.s[2] = qkv_w;      jobs.d[2] = wq_bf;  jobs.n[2] = TRD * D_;
    jobs.s[3] = out_proj_w; jobs.d[3] = wo_bf;  jobs.n[3] = D_ * D_;
    jobs.s[4] = to_out_w;   jobs.d[4] = wt_bf;  jobs.n[4] = D_ * D_;
    jobs.s[5] = gl_w;       jobs.d[5] = wg_bf;  jobs.n[5] = D_ * 2 * D_;
    jobs.s[6] = lin1_w;     jobs.d[6] = w1_bf;  jobs.n[6] = FF_ * D_;
    jobs.s[7] = lin2_w;     jobs.d[7] = w2_bf;  jobs.n[7] = D_ * FF_;
    cvt_kernel<<<dim3((MR_ * D_ / 4 + 255) / 256), blk256, 0, stream>>>(jobs);

    // 1. qkv_g = src @ in_proj_w^T + b                             -> buf0
    gemm_bf16_kernel<<<dim3(TRD / 128, MR_ / 128), blk256, 0, stream>>>(
        src_bf, D_, wi_bf, in_proj_b, buf0, TRD, D_, 0);
    // 2. global flash attention                                    -> buf1
    attn_global_mfma_kernel<<<dim3(S_ / 64, B_ * H_), blk256, 0, stream>>>(buf0, buf1);
    // 3. go = attn @ out_proj^T + b                                -> cat[:, :512]
    gemm_bf16_kernel<<<dim3(D_ / 128, MR_ / 128), blk256, 0, stream>>>(
        buf1, D_, wo_bf, out_proj_b, buf2, 2 * D_, D_, 0);
    // 4. x = LN(src)                                               -> buf1
    addln_kernel<float, float, ushort><<<dim3(MR_ / 4), blk256, 0, stream>>>(
        src, (const float*)nullptr, ln_g, ln_b, buf1);
    // 5. qkv_l = x @ qkv_w^T                                       -> buf0
    gemm_bf16_kernel<<<dim3(TRD / 128, MR_ / 128), blk256, 0, stream>>>(
        buf1, D_, wq_bf, nullptr, buf0, TRD, D_, 0);
    // 6. RoPE + q-scale in place
    rope_kernel<<<dim3((B_ * S_ * H_ * 32) / 256), blk256, 0, stream>>>(buf0);
    // 7. local windowed attention                                  -> buf1
    attn_local_mfma_kernel<<<dim3(S_ / 64, B_ * H_), blk256, 0, stream>>>(buf0, buf1);
    // 8. lo = lo_pre @ to_out^T                                    -> cat[:, 512:]
    gemm_bf16_kernel<<<dim3(D_ / 128, MR_ / 128), blk256, 0, stream>>>(
        buf1, D_, wt_bf, nullptr, buf2 + D_, 2 * D_, D_, 0);
    // 9. src2 = cat @ gl_w^T + b  (K=1024)                         -> buf1
    gemm_bf16_kernel<<<dim3(D_ / 128, MR_ / 128), blk256, 0, stream>>>(
        buf2, 2 * D_, wg_bf, gl_b, buf1, D_, 2 * D_, 0);
    // 10. h1 = LN(src + src2)                                      -> h1b
    addln_kernel<float, ushort, ushort><<<dim3(MR_ / 4), blk256, 0, stream>>>(
        src, buf1, norm1_g, norm1_b, h1b);
    // 11. ff1 = relu(h1 @ lin1^T + b)                              -> ff1
    gemm_bf16_kernel<<<dim3(FF_ / 128, MR_ / 128), blk256, 0, stream>>>(
        h1b, D_, w1_bf, lin1_b, ff1, FF_, D_, 1);
    // 12. ff2 = ff1 @ lin2^T + b  (K=2048)                         -> buf1
    gemm_bf16_kernel<<<dim3(D_ / 128, MR_ / 128), blk256, 0, stream>>>(
        ff1, FF_, w2_bf, lin2_b, buf1, D_, FF_, 0);
    // 13. out = LN(h1 + ff2)                                       -> d_out (fp32)
    addln_kernel<ushort, ushort, float><<<dim3(MR_ / 4), blk256, 0, stream>>>(
        h1b, buf1, norm2_g, norm2_b, out);
}

// Round 4
// 492.264 us; speedup vs baseline: 5.0718x; 1.1392x over previous
//
#include <hip/hip_runtime.h>
#include <math.h>

#define B_  4
#define S_  2048
#define D_  512
#define H_  8
#define FF_ 2048
#define W_  128
#define DH_ 64
#define NW_ 16
#define TRD (3*D_)   // 1536
#define MR_ (B_*S_)  // 8192 rows

typedef __attribute__((ext_vector_type(8))) short short8;
typedef __attribute__((ext_vector_type(4))) float f32x4;

__device__ __forceinline__ short f2bf(float f) {
    unsigned u = __float_as_uint(f);
    unsigned r = (u + 0x7fff + ((u >> 16) & 1)) >> 16;   // RNE
    return (short)r;
}
__device__ __forceinline__ float bf2f(ushort u) {
    return __uint_as_float(((unsigned)u) << 16);
}
__device__ __forceinline__ void gload_lds16(const ushort* g, short* l) {
    __builtin_amdgcn_global_load_lds(
        (const __attribute__((address_space(1))) void*)g,
        (__attribute__((address_space(3))) void*)l, 16, 0, 0);
}

// ---------------------------------------------------------------------------
// Fused fp32 -> bf16 conversion for src + 7 weight tensors.
// ---------------------------------------------------------------------------
struct CvtJobs { const float* s[8]; ushort* d[8]; int n[8]; };

__global__ __launch_bounds__(256) void cvt_kernel(CvtJobs jobs)
{
    int i4 = (blockIdx.x * 256 + threadIdx.x) * 4;
    #pragma unroll
    for (int j = 0; j < 8; j++) {
        if (i4 < jobs.n[j]) {
            float4 v = *(const float4*)(jobs.s[j] + i4);
            ushort4 o;
            o.x = (ushort)f2bf(v.x); o.y = (ushort)f2bf(v.y);
            o.z = (ushort)f2bf(v.z); o.w = (ushort)f2bf(v.w);
            *(ushort4*)(jobs.d[j] + i4) = o;
        }
    }
}

// ---------------------------------------------------------------------------
// bf16 MFMA GEMM, 128x128 tile, BK=64, global_load_lds staging with XOR
// swizzle: physical colgroup = logical colgroup ^ (row&7)  (colgroup = 8
// shorts = 16 B). Kills the 16-way fragment-read bank conflicts while
// keeping the DMA's lane-ordered destination layout.
// ---------------------------------------------------------------------------
__global__ __launch_bounds__(256) void gemm_bf16_kernel(
    const ushort* __restrict__ A, int lda,
    const ushort* __restrict__ Wt,     // [N][K] row-major
    const float* __restrict__ bias,
    ushort* __restrict__ C, int ldc,
    int K, int relu)
{
    __shared__ short As[128 * 64];
    __shared__ short Bs[128 * 64];
    const int tid  = threadIdx.x;
    const int w    = tid >> 6;
    const int lane = tid & 63;
    const int quad = lane >> 4;
    const int x    = lane & 15;
    const int wr = w >> 1, wc = w & 1;
    const int bm = blockIdx.y * 128;
    const int bn = blockIdx.x * 128;

    // staging: wave w rows [w*32, +32), chunk c = 8 rows; lane l -> row +l/8,
    // swizzled source colgroup (l&7)^(l>>3)
    const int srow = w * 32 + (lane >> 3);
    const int scol = ((lane & 7) ^ (lane >> 3)) * 8;

    f32x4 acc[4][4];
    #pragma unroll
    for (int i = 0; i < 4; i++)
        #pragma unroll
        for (int j = 0; j < 4; j++) acc[i][j] = (f32x4)0.f;

    for (int k0 = 0; k0 < K; k0 += 64) {
        __syncthreads();
        #pragma unroll
        for (int c = 0; c < 4; c++) {
            const ushort* ga = A + (size_t)(bm + srow + c * 8) * lda + k0 + scol;
            gload_lds16(ga, &As[(w * 32 + c * 8) * 64]);
            const ushort* gb = Wt + (size_t)(bn + srow + c * 8) * K + k0 + scol;
            gload_lds16(gb, &Bs[(w * 32 + c * 8) * 64]);
        }
        __syncthreads();

        #pragma unroll
        for (int kc = 0; kc < 2; kc++) {
            short8 af[4], bf[4];
            #pragma unroll
            for (int i = 0; i < 4; i++) {
                int row = wr * 64 + i * 16 + x;
                int pcg = (kc * 4 + quad) ^ (x & 7);
                af[i] = *(const short8*)&As[row * 64 + pcg * 8];
            }
            #pragma unroll
            for (int j = 0; j < 4; j++) {
                int row = wc * 64 + j * 16 + x;
                int pcg = (kc * 4 + quad) ^ (x & 7);
                bf[j] = *(const short8*)&Bs[row * 64 + pcg * 8];
            }
            #pragma unroll
            for (int i = 0; i < 4; i++)
                #pragma unroll
                for (int j = 0; j < 4; j++)
                    acc[i][j] = __builtin_amdgcn_mfma_f32_16x16x32_bf16(af[i], bf[j], acc[i][j], 0, 0, 0);
        }
    }

    #pragma unroll
    for (int i = 0; i < 4; i++) {
        #pragma unroll
        for (int r = 0; r < 4; r++) {
            size_t row = (size_t)(bm + wr * 64 + i * 16 + quad * 4 + r);
            #pragma unroll
            for (int j = 0; j < 4; j++) {
                int col = bn + wc * 64 + j * 16 + x;
                float v = acc[i][j][r] + (bias ? bias[col] : 0.f);
                if (relu) v = v > 0.f ? v : 0.f;
                C[row * ldc + col] = (ushort)f2bf(v);
            }
        }
    }
}

// ---------------------------------------------------------------------------
// LayerNorm over D=512, wave per row; templated dtypes.
// ---------------------------------------------------------------------------
__device__ __forceinline__ float wave_sum64(float v) {
    #pragma unroll
    for (int off = 32; off > 0; off >>= 1) v += __shfl_xor(v, off, 64);
    return v;
}
__device__ __forceinline__ void load8(const float* p, float* v) {
    *(float4*)&v[0] = *(const float4*)p;
    *(float4*)&v[4] = *(const float4*)(p + 4);
}
__device__ __forceinline__ void load8(const ushort* p, float* v) {
    short8 s = *(const short8*)p;
    #pragma unroll
    for (int i = 0; i < 8; i++) v[i] = bf2f((ushort)s[i]);
}
__device__ __forceinline__ void store8(float* p, const float* v) {
    *(float4*)p       = make_float4(v[0], v[1], v[2], v[3]);
    *(float4*)(p + 4) = make_float4(v[4], v[5], v[6], v[7]);
}
__device__ __forceinline__ void store8(ushort* p, const float* v) {
    short8 s;
    #pragma unroll
    for (int i = 0; i < 8; i++) s[i] = f2bf(v[i]);
    *(short8*)p = s;
}

template <typename TA, typename TB, typename TO>
__global__ __launch_bounds__(256) void addln_kernel(
    const TA* __restrict__ a, const TB* __restrict__ b,
    const float* __restrict__ g, const float* __restrict__ be,
    TO* __restrict__ out)
{
    const int lane = threadIdx.x & 63;
    const int row  = blockIdx.x * 4 + (threadIdx.x >> 6);
    const size_t base = (size_t)row * D_ + lane * 8;
    float v[8];
    load8(a + base, v);
    if (b) {
        float wv[8];
        load8(b + base, wv);
        #pragma unroll
        for (int i = 0; i < 8; i++) v[i] += wv[i];
    }
    float s = 0.f;
    #pragma unroll
    for (int i = 0; i < 8; i++) s += v[i];
    float mean = wave_sum64(s) * (1.0f / 512.0f);
    float vs = 0.f;
    #pragma unroll
    for (int i = 0; i < 8; i++) { float d = v[i] - mean; vs += d * d; }
    float var = wave_sum64(vs) * (1.0f / 512.0f);
    float r = rsqrtf(var + 1e-5f);
    const int c = lane * 8;
    float t[8];
    #pragma unroll
    for (int i = 0; i < 8; i++) t[i] = (v[i] - mean) * r * g[c + i] + be[c + i];
    store8(out + base, t);
}

// ---------------------------------------------------------------------------
// Transpose the V third of a qkv buffer into VT[b][h][d][s] (bf16), so
// attention can DMA-stage V^T tiles. LDS-tiled 64x64.
// Grid: (S/64, B*H), 256 threads.
// ---------------------------------------------------------------------------
__global__ __launch_bounds__(256) void transpose_v_kernel(
    const ushort* __restrict__ qkv, ushort* __restrict__ vt)
{
    __shared__ ushort T[64][72];
    const int t  = threadIdx.x;
    const int s0 = blockIdx.x * 64;
    const int bh = blockIdx.y;
    const int b = bh >> 3, h = bh & 7;
    {
        int row = t >> 2, col = (t & 3) * 16;
        const ushort* src = qkv + ((size_t)(b * S_) + s0 + row) * TRD + 2 * D_ + h * DH_ + col;
        *(short8*)&T[row][col]     = *(const short8*)src;
        *(short8*)&T[row][col + 8] = *(const short8*)(src + 8);
    }
    __syncthreads();
    {
        int d = t >> 2, sc = (t & 3) * 16;
        ushort tmp[16];
        #pragma unroll
        for (int k = 0; k < 16; k++) tmp[k] = T[sc + k][d];
        ushort* dst = vt + ((size_t)bh * DH_ + d) * S_ + s0 + sc;
        *(short8*)dst       = *(const short8*)&tmp[0];
        *(short8*)(dst + 8) = *(const short8*)&tmp[8];
    }
}

// ---------------------------------------------------------------------------
// Global attention, bf16 MFMA flash, K-tile 128, DMA-staged K and V^T with
// XOR-swizzled LDS layout. Block 256 = 4 waves; wave w owns 16 q-rows.
// ---------------------------------------------------------------------------
#define PP 136   // P pitch (shorts): padded, 2-way banks only

__global__ __launch_bounds__(256) void attn_global_mfma_kernel(
    const ushort* __restrict__ qkv, const ushort* __restrict__ vt,
    ushort* __restrict__ out)
{
    __shared__ short Ks[128 * 64];   // [key][dim], swizzled
    __shared__ short Vt[64 * 128];   // [dim][key], swizzled
    __shared__ short Pb[4 * 16 * PP];

    const int tid  = threadIdx.x;
    const int w    = tid >> 6;
    const int lane = tid & 63;
    const int quad = lane >> 4;
    const int x    = lane & 15;
    const int bh = blockIdx.y;
    const int b = bh >> 3, h = bh & 7;
    const int qbase = blockIdx.x * 64;
    const size_t bS = (size_t)b * S_;
    const size_t vbase = (size_t)bh * DH_;

    short8 aq[2];
    {
        const ushort* qp = qkv + (bS + qbase + w * 16 + x) * TRD + h * DH_;
        #pragma unroll
        for (int kc = 0; kc < 2; kc++) {
            short8 raw = *(const short8*)(qp + kc * 32 + quad * 8);
            #pragma unroll
            for (int j = 0; j < 8; j++)
                aq[kc][j] = f2bf(bf2f((ushort)raw[j]) * 0.125f);
        }
    }

    f32x4 o[4];
    #pragma unroll
    for (int dt = 0; dt < 4; dt++) o[dt] = (f32x4)0.f;
    float m[4], l[4];
    #pragma unroll
    for (int r = 0; r < 4; r++) { m[r] = -3.0e38f; l[r] = 0.f; }

    short* Pw = &Pb[w * 16 * PP];

    for (int kt = 0; kt < S_; kt += 128) {
        __syncthreads();
        // K: wave w keys [w*32, +32), 4 chunks of 8 rows, swizzled source col
        #pragma unroll
        for (int c = 0; c < 4; c++) {
            int key = w * 32 + c * 8 + (lane >> 3);
            int cg  = (lane & 7) ^ (lane >> 3);
            const ushort* gk = qkv + (bS + kt + key) * TRD + D_ + h * DH_ + cg * 8;
            gload_lds16(gk, &Ks[(w * 32 + c * 8) * 64]);
        }
        // V^T: wave w d-rows [w*16, +16), 4 chunks of 4 rows (128 shorts/row)
        #pragma unroll
        for (int c = 0; c < 4; c++) {
            int row = w * 16 + c * 4 + (lane >> 4);
            int cg  = (lane & 15) ^ (row & 7);
            const ushort* gv = vt + (vbase + row) * S_ + kt + cg * 8;
            gload_lds16(gv, &Vt[(w * 16 + c * 4) * 128]);
        }
        __syncthreads();

        // S = Q K^T : 8 n-tiles of 16 keys
        f32x4 sc[8];
        #pragma unroll
        for (int nt = 0; nt < 8; nt++) {
            sc[nt] = (f32x4)0.f;
            #pragma unroll
            for (int kc = 0; kc < 2; kc++) {
                int pcg = (kc * 4 + quad) ^ (x & 7);
                short8 bk = *(const short8*)&Ks[(nt * 16 + x) * 64 + pcg * 8];
                sc[nt] = __builtin_amdgcn_mfma_f32_16x16x32_bf16(aq[kc], bk, sc[nt], 0, 0, 0);
            }
        }

        #pragma unroll
        for (int r = 0; r < 4; r++) {
            float mx = sc[0][r];
            #pragma unroll
            for (int nt = 1; nt < 8; nt++) mx = fmaxf(mx, sc[nt][r]);
            #pragma unroll
            for (int off = 1; off < 16; off <<= 1) mx = fmaxf(mx, __shfl_xor(mx, off, 64));
            float mnew = fmaxf(m[r], mx);
            float alpha = __expf(m[r] - mnew);
            m[r] = mnew;
            float psum = 0.f;
            #pragma unroll
            for (int nt = 0; nt < 8; nt++) {
                float p = __expf(sc[nt][r] - mnew);
                sc[nt][r] = p;
                psum += p;
            }
            #pragma unroll
            for (int off = 1; off < 16; off <<= 1) psum += __shfl_xor(psum, off, 64);
            l[r] = l[r] * alpha + psum;
            #pragma unroll
            for (int dt = 0; dt < 4; dt++) o[dt][r] *= alpha;
            #pragma unroll
            for (int nt = 0; nt < 8; nt++)
                Pw[(quad * 4 + r) * PP + nt * 16 + x] = f2bf(sc[nt][r]);
        }
        asm volatile("s_waitcnt lgkmcnt(0)" ::: "memory");

        // O += P V : kc over 128 keys
        #pragma unroll
        for (int kc = 0; kc < 4; kc++) {
            short8 ap = *(const short8*)&Pw[x * PP + kc * 32 + quad * 8];
            #pragma unroll
            for (int dt = 0; dt < 4; dt++) {
                int pcg = (kc * 4 + quad) ^ (x & 7);
                short8 bv = *(const short8*)&Vt[(dt * 16 + x) * 128 + pcg * 8];
                o[dt] = __builtin_amdgcn_mfma_f32_16x16x32_bf16(ap, bv, o[dt], 0, 0, 0);
            }
        }
    }

    #pragma unroll
    for (int r = 0; r < 4; r++) {
        float inv = 1.0f / l[r];
        size_t rowbase = (bS + qbase + w * 16 + quad * 4 + r) * D_ + h * DH_;
        #pragma unroll
        for (int dt = 0; dt < 4; dt++)
            out[rowbase + dt * 16 + x] = (ushort)f2bf(o[dt][r] * inv);
    }
}

// ---------------------------------------------------------------------------
// RoPE (+0.125 on q) in place on bf16 local qkv (q,k columns only).
// ---------------------------------------------------------------------------
__global__ __launch_bounds__(256) void rope_kernel(ushort* __restrict__ qkv)
{
    int idx = blockIdx.x * 256 + threadIdx.x;
    int d  = idx & 31;
    int h  = (idx >> 5) & 7;
    int bs = idx >> 8;
    int pos = bs & (S_ - 1);
    float inv_freq = exp2f(-(float)d * (2.0f / 64.0f) * 13.287712379549449f);
    float ang = (float)pos * inv_freq;
    float sn, cs;
    sincosf(ang, &sn, &cs);
    ushort* base = qkv + (size_t)bs * TRD + h * DH_;
    float q1 = bf2f(base[d]), q2 = bf2f(base[d + 32]);
    base[d]      = (ushort)f2bf((q1 * cs - q2 * sn) * 0.125f);
    base[d + 32] = (ushort)f2bf((q2 * cs + q1 * sn) * 0.125f);
    ushort* kb = base + D_;
    float k1 = bf2f(kb[d]), k2 = bf2f(kb[d + 32]);
    kb[d]      = (ushort)f2bf(k1 * cs - k2 * sn);
    kb[d + 32] = (ushort)f2bf(k2 * cs + k1 * sn);
}

// ---------------------------------------------------------------------------
// Local windowed attention, bf16 MFMA flash, K-tile 128. Block = 64 queries
// inside window n; tiles: prev window (kt=0, unmasked, skipped if n==0) and
// own window (kt=1, causal mask).
// ---------------------------------------------------------------------------
__global__ __launch_bounds__(256) void attn_local_mfma_kernel(
    const ushort* __restrict__ qkv, const ushort* __restrict__ vt,
    ushort* __restrict__ out)
{
    __shared__ short Ks[128 * 64];
    __shared__ short Vt[64 * 128];
    __shared__ short Pb[4 * 16 * PP];

    const int tid  = threadIdx.x;
    const int w    = tid >> 6;
    const int lane = tid & 63;
    const int quad = lane >> 4;
    const int x    = lane & 15;
    const int bh = blockIdx.y;
    const int b = bh >> 3, h = bh & 7;
    const int qbase = blockIdx.x * 64;
    const int n = qbase >> 7;
    const size_t bS = (size_t)b * S_;
    const size_t vbase = (size_t)bh * DH_;

    short8 aq[2];
    {
        const ushort* qp = qkv + (bS + qbase + w * 16 + x) * TRD + h * DH_;
        #pragma unroll
        for (int kc = 0; kc < 2; kc++)
            aq[kc] = *(const short8*)(qp + kc * 32 + quad * 8);
    }

    f32x4 o[4];
    #pragma unroll
    for (int dt = 0; dt < 4; dt++) o[dt] = (f32x4)0.f;
    float m[4], l[4];
    #pragma unroll
    for (int r = 0; r < 4; r++) { m[r] = -3.0e38f; l[r] = 0.f; }

    short* Pw = &Pb[w * 16 * PP];

    for (int kt = 0; kt < 2; kt++) {
        const int kbase = (n - 1) * 128 + kt * 128;
        if (kbase < 0) continue;       // uniform per block
        __syncthreads();
        #pragma unroll
        for (int c = 0; c < 4; c++) {
            int key = w * 32 + c * 8 + (lane >> 3);
            int cg  = (lane & 7) ^ (lane >> 3);
            const ushort* gk = qkv + (bS + kbase + key) * TRD + D_ + h * DH_ + cg * 8;
            gload_lds16(gk, &Ks[(w * 32 + c * 8) * 64]);
        }
        #pragma unroll
        for (int c = 0; c < 4; c++) {
            int row = w * 16 + c * 4 + (lane >> 4);
            int cg  = (lane & 15) ^ (row & 7);
            const ushort* gv = vt + (vbase + row) * S_ + kbase + cg * 8;
            gload_lds16(gv, &Vt[(w * 16 + c * 4) * 128]);
        }
        __syncthreads();

        f32x4 sc[8];
        #pragma unroll
        for (int nt = 0; nt < 8; nt++) {
            sc[nt] = (f32x4)0.f;
            #pragma unroll
            for (int kc = 0; kc < 2; kc++) {
                int pcg = (kc * 4 + quad) ^ (x & 7);
                short8 bk = *(const short8*)&Ks[(nt * 16 + x) * 64 + pcg * 8];
                sc[nt] = __builtin_amdgcn_mfma_f32_16x16x32_bf16(aq[kc], bk, sc[nt], 0, 0, 0);
            }
        }
        if (kt == 1) {   // causal mask: kp = kbase + nt*16 + x vs qp
            #pragma unroll
            for (int nt = 0; nt < 8; nt++) {
                int kp = kbase + nt * 16 + x;
                #pragma unroll
                for (int r = 0; r < 4; r++) {
                    int qp = qbase + w * 16 + quad * 4 + r;
                    if (kp > qp) sc[nt][r] = -3.0e38f;
                }
            }
        }

        #pragma unroll
        for (int r = 0; r < 4; r++) {
            float mx = sc[0][r];
            #pragma unroll
            for (int nt = 1; nt < 8; nt++) mx = fmaxf(mx, sc[nt][r]);
            #pragma unroll
            for (int off = 1; off < 16; off <<= 1) mx = fmaxf(mx, __shfl_xor(mx, off, 64));
            float mnew = fmaxf(m[r], mx);
            float alpha = __expf(m[r] - mnew);
            m[r] = mnew;
            float psum = 0.f;
            #pragma unroll
            for (int nt = 0; nt < 8; nt++) {
                float p = __expf(sc[nt][r] - mnew);
                sc[nt][r] = p;
                psum += p;
            }
            #pragma unroll
            for (int off = 1; off < 16; off <<= 1) psum += __shfl_xor(psum, off, 64);
            l[r] = l[r] * alpha + psum;
            #pragma unroll
            for (int dt = 0; dt < 4; dt++) o[dt][r] *= alpha;
            #pragma unroll
            for (int nt = 0; nt < 8; nt++)
                Pw[(quad * 4 + r) * PP + nt * 16 + x] = f2bf(sc[nt][r]);
        }
        asm volatile("s_waitcnt lgkmcnt(0)" ::: "memory");

        #pragma unroll
        for (int kc = 0; kc < 4; kc++) {
            short8 ap = *(const short8*)&Pw[x * PP + kc * 32 + quad * 8];
            #pragma unroll
            for (int dt = 0; dt < 4; dt++) {
                int pcg = (kc * 4 + quad) ^ (x & 7);
                short8 bv = *(const short8*)&Vt[(dt * 16 + x) * 128 + pcg * 8];
                o[dt] = __builtin_amdgcn_mfma_f32_16x16x32_bf16(ap, bv, o[dt], 0, 0, 0);
            }
        }
    }

    #pragma unroll
    for (int r = 0; r < 4; r++) {
        float inv = 1.0f / l[r];
        size_t rowbase = (bS + qbase + w * 16 + quad * 4 + r) * D_ + h * DH_;
        #pragma unroll
        for (int dt = 0; dt < 4; dt++)
            out[rowbase + dt * 16 + x] = (ushort)f2bf(o[dt][r] * inv);
    }
}

// ---------------------------------------------------------------------------
extern "C" void kernel_launch(void* const* d_in, const int* in_sizes, int n_in,
                              void* d_out, int out_size, void* d_ws, size_t ws_size,
                              hipStream_t stream)
{
    (void)in_sizes; (void)n_in; (void)out_size; (void)ws_size;
    const float* src        = (const float*)d_in[0];
    const float* in_proj_w  = (const float*)d_in[1];
    const float* in_proj_b  = (const float*)d_in[2];
    const float* out_proj_w = (const float*)d_in[3];
    const float* out_proj_b = (const float*)d_in[4];
    const float* ln_g       = (const float*)d_in[5];
    const float* ln_b       = (const float*)d_in[6];
    const float* qkv_w      = (const float*)d_in[7];
    const float* to_out_w   = (const float*)d_in[8];
    const float* gl_w       = (const float*)d_in[9];
    const float* gl_b       = (const float*)d_in[10];
    const float* norm1_g    = (const float*)d_in[11];
    const float* norm1_b    = (const float*)d_in[12];
    const float* lin1_w     = (const float*)d_in[13];
    const float* lin1_b     = (const float*)d_in[14];
    const float* lin2_w     = (const float*)d_in[15];
    const float* lin2_b     = (const float*)d_in[16];
    const float* norm2_g    = (const float*)d_in[17];
    const float* norm2_b    = (const float*)d_in[18];
    float* out = (float*)d_out;

    // --- bf16 workspace layout (ushorts), ~93.3 MB ---
    ushort* ws16   = (ushort*)d_ws;
    ushort* src_bf = ws16;
    ushort* wi_bf  = src_bf + (size_t)MR_ * D_;
    ushort* wq_bf  = wi_bf  + TRD * D_;
    ushort* wo_bf  = wq_bf  + TRD * D_;
    ushort* wt_bf  = wo_bf  + D_ * D_;
    ushort* wg_bf  = wt_bf  + D_ * D_;
    ushort* w1_bf  = wg_bf  + D_ * 2 * D_;
    ushort* w2_bf  = w1_bf  + FF_ * D_;
    ushort* buf1   = w2_bf  + D_ * FF_;             // 8192*512
    ushort* h1b    = buf1   + (size_t)MR_ * D_;     // 8192*512
    ushort* buf0   = h1b    + (size_t)MR_ * D_;     // 8192*1536 (qkv)
    ushort* buf2   = buf0   + (size_t)MR_ * TRD;    // 8192*1024 (cat)
    ushort* vtg    = buf2   + (size_t)MR_ * 2 * D_; // 8192*512  V^T global
    ushort* vtl    = vtg    + (size_t)MR_ * D_;     // 8192*512  V^T local
    ushort* ff1    = buf0;                          // overlays buf0+buf2

    dim3 blk256(256);

    // 0. fp32 -> bf16 conversions
    CvtJobs jobs;
    jobs.s[0] = src;        jobs.d[0] = src_bf; jobs.n[0] = MR_ * D_;
    jobs.s[1] = in_proj_w;  jobs.d[1] = wi_bf;  jobs.n[1] = TRD * D_;
    jobs.s[2] = qkv_w;      jobs.d[2] = wq_bf;  jobs.n[2] = TRD * D_;
    jobs.s[3] = out_proj_w; jobs.d[3] = wo_bf;  jobs.n[3] = D_ * D_;
    jobs.s[4] = to_out_w;   jobs.d[4] = wt_bf;  jobs.n[4] = D_ * D_;
    jobs.s[5] = gl_w;       jobs.d[5] = wg_bf;  jobs.n[5] = D_ * 2 * D_;
    jobs.s[6] = lin1_w;     jobs.d[6] = w1_bf;  jobs.n[6] = FF_ * D_;
    jobs.s[7] = lin2_w;     jobs.d[7] = w2_bf;  jobs.n[7] = D_ * FF_;
    cvt_kernel<<<dim3((MR_ * D_ / 4 + 255) / 256), blk256, 0, stream>>>(jobs);

    // 1. qkv_g = src @ in_proj^T + b                              -> buf0
    gemm_bf16_kernel<<<dim3(TRD / 128, MR_ / 128), blk256, 0, stream>>>(
        src_bf, D_, wi_bf, in_proj_b, buf0, TRD, D_, 0);
    // 1b. V^T for global attention                                -> vtg
    transpose_v_kernel<<<dim3(S_ / 64, B_ * H_), blk256, 0, stream>>>(buf0, vtg);
    // 2. global flash attention                                   -> buf1
    attn_global_mfma_kernel<<<dim3(S_ / 64, B_ * H_), blk256, 0, stream>>>(buf0, vtg, buf1);
    // 3. go = attn @ out_proj^T + b                               -> cat[:, :512]
    gemm_bf16_kernel<<<dim3(D_ / 128, MR_ / 128), blk256, 0, stream>>>(
        buf1, D_, wo_bf, out_proj_b, buf2, 2 * D_, D_, 0);
    // 4. x = LN(src)                                              -> buf1
    addln_kernel<float, float, ushort><<<dim3(MR_ / 4), blk256, 0, stream>>>(
        src, (const float*)nullptr, ln_g, ln_b, buf1);
    // 5. qkv_l = x @ qkv_w^T                                      -> buf0
    gemm_bf16_kernel<<<dim3(TRD / 128, MR_ / 128), blk256, 0, stream>>>(
        buf1, D_, wq_bf, nullptr, buf0, TRD, D_, 0);
    // 5b. V^T for local attention                                 -> vtl
    transpose_v_kernel<<<dim3(S_ / 64, B_ * H_), blk256, 0, stream>>>(buf0, vtl);
    // 6. RoPE + q-scale in place (q,k only; V untouched)
    rope_kernel<<<dim3((B_ * S_ * H_ * 32) / 256), blk256, 0, stream>>>(buf0);
    // 7. local windowed attention                                 -> buf1
    attn_local_mfma_kernel<<<dim3(S_ / 64, B_ * H_), blk256, 0, stream>>>(buf0, vtl, buf1);
    // 8. lo = lo_pre @ to_out^T                                   -> cat[:, 512:]
    gemm_bf16_kernel<<<dim3(D_ / 128, MR_ / 128), blk256, 0, stream>>>(
        buf1, D_, wt_bf, nullptr, buf2 + D_, 2 * D_, D_, 0);
    // 9. src2 = cat @ gl_w^T + b  (K=1024)                        -> buf1
    gemm_bf16_kernel<<<dim3(D_ / 128, MR_ / 128), blk256, 0, stream>>>(
        buf2, 2 * D_, wg_bf, gl_b, buf1, D_, 2 * D_, 0);
    // 10. h1 = LN(src + src2)                                     -> h1b
    addln_kernel<float, ushort, ushort><<<dim3(MR_ / 4), blk256, 0, stream>>>(
        src, buf1, norm1_g, norm1_b, h1b);
    // 11. ff1 = relu(h1 @ lin1^T + b)                             -> ff1
    gemm_bf16_kernel<<<dim3(FF_ / 128, MR_ / 128), blk256, 0, stream>>>(
        h1b, D_, w1_bf, lin1_b, ff1, FF_, D_, 1);
    // 12. ff2 = ff1 @ lin2^T + b  (K=2048)                        -> buf1
    gemm_bf16_kernel<<<dim3(D_ / 128, MR_ / 128), blk256, 0, stream>>>(
        ff1, FF_, w2_bf, lin2_b, buf1, D_, FF_, 0);
    // 13. out = LN(h1 + ff2)                                      -> d_out (fp32)
    addln_kernel<ushort, ushort, float><<<dim3(MR_ / 4), blk256, 0, stream>>>(
        h1b, buf1, norm2_g, norm2_b, out);
}

// Round 5
// 462.497 us; speedup vs baseline: 5.3982x; 1.0644x over previous
//
#include <hip/hip_runtime.h>
#include <math.h>

#define B_  4
#define S_  2048
#define D_  512
#define H_  8
#define FF_ 2048
#define W_  128
#define DH_ 64
#define NW_ 16
#define TRD (3*D_)   // 1536
#define MR_ (B_*S_)  // 8192 rows

typedef __attribute__((ext_vector_type(8)))  short short8;
typedef __attribute__((ext_vector_type(4)))  short short4v;
typedef __attribute__((ext_vector_type(4)))  float f32x4;
typedef __attribute__((ext_vector_type(16))) float f32x16;

__device__ __forceinline__ short f2bf(float f) {
    unsigned u = __float_as_uint(f);
    unsigned r = (u + 0x7fff + ((u >> 16) & 1)) >> 16;   // RNE
    return (short)r;
}
__device__ __forceinline__ float bf2f(ushort u) {
    return __uint_as_float(((unsigned)u) << 16);
}
__device__ __forceinline__ void gload_lds16(const ushort* g, short* l) {
    __builtin_amdgcn_global_load_lds(
        (const __attribute__((address_space(1))) void*)g,
        (__attribute__((address_space(3))) void*)l, 16, 0, 0);
}

// ---------------------------------------------------------------------------
// Fused fp32 -> bf16 conversion for src + 7 weight tensors.
// ---------------------------------------------------------------------------
struct CvtJobs { const float* s[8]; ushort* d[8]; int n[8]; };

__global__ __launch_bounds__(256) void cvt_kernel(CvtJobs jobs)
{
    int i4 = (blockIdx.x * 256 + threadIdx.x) * 4;
    #pragma unroll
    for (int j = 0; j < 8; j++) {
        if (i4 < jobs.n[j]) {
            float4 v = *(const float4*)(jobs.s[j] + i4);
            ushort4 o;
            o.x = (ushort)f2bf(v.x); o.y = (ushort)f2bf(v.y);
            o.z = (ushort)f2bf(v.z); o.w = (ushort)f2bf(v.w);
            *(ushort4*)(jobs.d[j] + i4) = o;
        }
    }
}

// ---------------------------------------------------------------------------
// bf16 MFMA GEMM, 128x128 tile, BK=64, global_load_lds + XOR swizzle (R3).
// ---------------------------------------------------------------------------
__global__ __launch_bounds__(256) void gemm_bf16_kernel(
    const ushort* __restrict__ A, int lda,
    const ushort* __restrict__ Wt,
    const float* __restrict__ bias,
    ushort* __restrict__ C, int ldc,
    int K, int relu)
{
    __shared__ short As[128 * 64];
    __shared__ short Bs[128 * 64];
    const int tid  = threadIdx.x;
    const int w    = tid >> 6;
    const int lane = tid & 63;
    const int quad = lane >> 4;
    const int x    = lane & 15;
    const int wr = w >> 1, wc = w & 1;
    const int bm = blockIdx.y * 128;
    const int bn = blockIdx.x * 128;

    const int srow = w * 32 + (lane >> 3);
    const int scol = ((lane & 7) ^ (lane >> 3)) * 8;

    f32x4 acc[4][4];
    #pragma unroll
    for (int i = 0; i < 4; i++)
        #pragma unroll
        for (int j = 0; j < 4; j++) acc[i][j] = (f32x4)0.f;

    for (int k0 = 0; k0 < K; k0 += 64) {
        __syncthreads();
        #pragma unroll
        for (int c = 0; c < 4; c++) {
            const ushort* ga = A + (size_t)(bm + srow + c * 8) * lda + k0 + scol;
            gload_lds16(ga, &As[(w * 32 + c * 8) * 64]);
            const ushort* gb = Wt + (size_t)(bn + srow + c * 8) * K + k0 + scol;
            gload_lds16(gb, &Bs[(w * 32 + c * 8) * 64]);
        }
        __syncthreads();

        #pragma unroll
        for (int kc = 0; kc < 2; kc++) {
            short8 af[4], bf[4];
            #pragma unroll
            for (int i = 0; i < 4; i++) {
                int row = wr * 64 + i * 16 + x;
                int pcg = (kc * 4 + quad) ^ (x & 7);
                af[i] = *(const short8*)&As[row * 64 + pcg * 8];
            }
            #pragma unroll
            for (int j = 0; j < 4; j++) {
                int row = wc * 64 + j * 16 + x;
                int pcg = (kc * 4 + quad) ^ (x & 7);
                bf[j] = *(const short8*)&Bs[row * 64 + pcg * 8];
            }
            #pragma unroll
            for (int i = 0; i < 4; i++)
                #pragma unroll
                for (int j = 0; j < 4; j++)
                    acc[i][j] = __builtin_amdgcn_mfma_f32_16x16x32_bf16(af[i], bf[j], acc[i][j], 0, 0, 0);
        }
    }

    #pragma unroll
    for (int i = 0; i < 4; i++) {
        #pragma unroll
        for (int r = 0; r < 4; r++) {
            size_t row = (size_t)(bm + wr * 64 + i * 16 + quad * 4 + r);
            #pragma unroll
            for (int j = 0; j < 4; j++) {
                int col = bn + wc * 64 + j * 16 + x;
                float v = acc[i][j][r] + (bias ? bias[col] : 0.f);
                if (relu) v = v > 0.f ? v : 0.f;
                C[row * ldc + col] = (ushort)f2bf(v);
            }
        }
    }
}

// ---------------------------------------------------------------------------
// LayerNorm over D=512, wave per row; templated dtypes.
// ---------------------------------------------------------------------------
__device__ __forceinline__ float wave_sum64(float v) {
    #pragma unroll
    for (int off = 32; off > 0; off >>= 1) v += __shfl_xor(v, off, 64);
    return v;
}
__device__ __forceinline__ void load8(const float* p, float* v) {
    *(float4*)&v[0] = *(const float4*)p;
    *(float4*)&v[4] = *(const float4*)(p + 4);
}
__device__ __forceinline__ void load8(const ushort* p, float* v) {
    short8 s = *(const short8*)p;
    #pragma unroll
    for (int i = 0; i < 8; i++) v[i] = bf2f((ushort)s[i]);
}
__device__ __forceinline__ void store8(float* p, const float* v) {
    *(float4*)p       = make_float4(v[0], v[1], v[2], v[3]);
    *(float4*)(p + 4) = make_float4(v[4], v[5], v[6], v[7]);
}
__device__ __forceinline__ void store8(ushort* p, const float* v) {
    short8 s;
    #pragma unroll
    for (int i = 0; i < 8; i++) s[i] = f2bf(v[i]);
    *(short8*)p = s;
}

template <typename TA, typename TB, typename TO>
__global__ __launch_bounds__(256) void addln_kernel(
    const TA* __restrict__ a, const TB* __restrict__ b,
    const float* __restrict__ g, const float* __restrict__ be,
    TO* __restrict__ out)
{
    const int lane = threadIdx.x & 63;
    const int row  = blockIdx.x * 4 + (threadIdx.x >> 6);
    const size_t base = (size_t)row * D_ + lane * 8;
    float v[8];
    load8(a + base, v);
    if (b) {
        float wv[8];
        load8(b + base, wv);
        #pragma unroll
        for (int i = 0; i < 8; i++) v[i] += wv[i];
    }
    float s = 0.f;
    #pragma unroll
    for (int i = 0; i < 8; i++) s += v[i];
    float mean = wave_sum64(s) * (1.0f / 512.0f);
    float vs = 0.f;
    #pragma unroll
    for (int i = 0; i < 8; i++) { float d = v[i] - mean; vs += d * d; }
    float var = wave_sum64(vs) * (1.0f / 512.0f);
    float r = rsqrtf(var + 1e-5f);
    const int c = lane * 8;
    float t[8];
    #pragma unroll
    for (int i = 0; i < 8; i++) t[i] = (v[i] - mean) * r * g[c + i] + be[c + i];
    store8(out + base, t);
}

// ---------------------------------------------------------------------------
// Transpose V third of qkv into VT[b][h][d][s] (bf16). Grid (S/64, B*H).
// ---------------------------------------------------------------------------
__global__ __launch_bounds__(256) void transpose_v_kernel(
    const ushort* __restrict__ qkv, ushort* __restrict__ vt)
{
    __shared__ ushort T[64][72];
    const int t  = threadIdx.x;
    const int s0 = blockIdx.x * 64;
    const int bh = blockIdx.y;
    const int b = bh >> 3, h = bh & 7;
    {
        int row = t >> 2, col = (t & 3) * 16;
        const ushort* src = qkv + ((size_t)(b * S_) + s0 + row) * TRD + 2 * D_ + h * DH_ + col;
        *(short8*)&T[row][col]     = *(const short8*)src;
        *(short8*)&T[row][col + 8] = *(const short8*)(src + 8);
    }
    __syncthreads();
    {
        int d = t >> 2, sc = (t & 3) * 16;
        ushort tmp[16];
        #pragma unroll
        for (int k = 0; k < 16; k++) tmp[k] = T[sc + k][d];
        ushort* dst = vt + ((size_t)bh * DH_ + d) * S_ + s0 + sc;
        *(short8*)dst       = *(const short8*)&tmp[0];
        *(short8*)(dst + 8) = *(const short8*)&tmp[8];
    }
}

// ---------------------------------------------------------------------------
// Attention core (32x32x16 MFMA, no-max softmax). Block = 128 thr = 2 waves,
// wave owns 32 q-rows. k-tile 64. Q in registers; Ks[key][d] / Vt[d][key]
// DMA-staged with XOR swizzle; P[q][key] per-wave pitch 72 (4-row quad spacing
// = 16 banks -> conflict-free scalar writes).
// 32x32 layouts (m74/m101): A[m=lane&31][k=(lane>>5)*8+j]; C/D col=lane&31,
// row=(reg&3)+8*(reg>>2)+4*(lane>>5).
// QK^T: D[q][key] (A=Q, B=Ks). PV: D[d][q] = Vt . P^T (A=Vt, B=P).
// Epilogue: O^T -> LDS (own P region) -> row-major vector store.
// ---------------------------------------------------------------------------
#define PPW 72   // P pitch in shorts

template <int LOCAL>
__global__ __launch_bounds__(128) void attn_kernel(
    const ushort* __restrict__ qkv, const ushort* __restrict__ vt,
    ushort* __restrict__ out)
{
    __shared__ short Ks[64 * 64];
    __shared__ short Vt[64 * 64];
    __shared__ short Pb[2 * 32 * PPW];
    __shared__ float Lw[2][32];

    const int tid  = threadIdx.x;
    const int w    = tid >> 6;
    const int lane = tid & 63;
    const int half = lane >> 5;
    const int c    = lane & 31;
    const int bh = blockIdx.y;
    const int b = bh >> 3, h = bh & 7;
    const int qbase = blockIdx.x * 64;
    const size_t bS = (size_t)b * S_;
    const size_t vbase = (size_t)bh * DH_;

    // Q fragments in registers; global branch folds 0.125 scale (local q is
    // pre-scaled by rope_kernel).
    short8 aq[4];
    {
        const ushort* qp = qkv + (bS + qbase + w * 32 + c) * TRD + h * DH_;
        #pragma unroll
        for (int kc = 0; kc < 4; kc++) {
            short8 raw = *(const short8*)(qp + kc * 16 + half * 8);
            if (LOCAL) {
                aq[kc] = raw;
            } else {
                #pragma unroll
                for (int j = 0; j < 8; j++)
                    aq[kc][j] = f2bf(bf2f((ushort)raw[j]) * 0.125f);
            }
        }
    }

    f32x16 ot[2];
    #pragma unroll
    for (int dt = 0; dt < 2; dt++) ot[dt] = (f32x16)0.f;
    float lp[16];
    #pragma unroll
    for (int r = 0; r < 16; r++) lp[r] = 0.f;

    short* Pw = &Pb[w * 32 * PPW];
    const int nkt = LOCAL ? 4 : (S_ / 64);

    for (int kt = 0; kt < nkt; kt++) {
        const int kbase = LOCAL ? ((qbase >> 7) * 128 - 128 + kt * 64) : kt * 64;
        if (LOCAL) {
            if (kbase < 0 || kbase > qbase + 63) continue;   // uniform per block
        }
        const bool diag = LOCAL && (kbase == qbase);

        __syncthreads();
        // stage K tile [64 key][64 d] and V^T tile [64 d][64 key], 4 DMA each
        #pragma unroll
        for (int cc = 0; cc < 4; cc++) {
            int row = w * 32 + cc * 8 + (lane >> 3);
            int cg  = (lane & 7) ^ (lane >> 3);
            const ushort* gk = qkv + (bS + kbase + row) * TRD + D_ + h * DH_ + cg * 8;
            gload_lds16(gk, &Ks[(w * 32 + cc * 8) * 64]);
            const ushort* gv = vt + (vbase + row) * S_ + kbase + cg * 8;
            gload_lds16(gv, &Vt[(w * 32 + cc * 8) * 64]);
        }
        __syncthreads();

        // S = Q K^T : 2 n-tiles of 32 keys
        f32x16 sc[2];
        #pragma unroll
        for (int nt = 0; nt < 2; nt++) {
            sc[nt] = (f32x16)0.f;
            #pragma unroll
            for (int kc = 0; kc < 4; kc++) {
                int row = nt * 32 + c;
                int pcg = (kc * 2 + half) ^ (row & 7);
                short8 bk = *(const short8*)&Ks[row * 64 + pcg * 8];
                sc[nt] = __builtin_amdgcn_mfma_f32_32x32x16_bf16(aq[kc], bk, sc[nt], 0, 0, 0);
            }
        }

        // exp + per-lane l partials + P write (no max, no shuffles)
        #pragma unroll
        for (int nt = 0; nt < 2; nt++) {
            #pragma unroll
            for (int r = 0; r < 16; r++) {
                int qrow = (r & 3) + 8 * (r >> 2) + 4 * half;
                float p;
                if (diag) {
                    bool valid = (kbase + nt * 32 + c) <= (qbase + w * 32 + qrow);
                    p = valid ? __expf(sc[nt][r]) : 0.f;
                } else {
                    p = __expf(sc[nt][r]);
                }
                lp[r] += p;
                Pw[qrow * PPW + nt * 32 + c] = f2bf(p);
            }
        }
        asm volatile("s_waitcnt lgkmcnt(0)" ::: "memory");   // own-wave P visible

        // O^T += V^T P^T : D[d][q], A=Vt, B=P
        #pragma unroll
        for (int kc = 0; kc < 4; kc++) {
            short8 bp = *(const short8*)&Pw[c * PPW + kc * 16 + half * 8];
            #pragma unroll
            for (int dt = 0; dt < 2; dt++) {
                int row = dt * 32 + c;
                int pcg = (kc * 2 + half) ^ (row & 7);
                short8 av = *(const short8*)&Vt[row * 64 + pcg * 8];
                ot[dt] = __builtin_amdgcn_mfma_f32_32x32x16_bf16(av, bp, ot[dt], 0, 0, 0);
            }
        }
    }

    // --- reduce l across the 32 columns (once) ---
    #pragma unroll
    for (int r = 0; r < 16; r++) {
        float v = lp[r];
        #pragma unroll
        for (int off = 1; off < 32; off <<= 1) v += __shfl_xor(v, off, 64);
        lp[r] = v;
    }
    if (c == 0) {
        #pragma unroll
        for (int r = 0; r < 16; r++)
            Lw[w][(r & 3) + 8 * (r >> 2) + 4 * half] = lp[r];
    }
    asm volatile("s_waitcnt lgkmcnt(0)" ::: "memory");
    __builtin_amdgcn_wave_barrier();
    float inv = 1.0f / Lw[w][c];   // this lane's q-column = c

    // --- O^T -> own P region (b64 packs), then row-major read + store ---
    #pragma unroll
    for (int dt = 0; dt < 2; dt++) {
        #pragma unroll
        for (int rq = 0; rq < 4; rq++) {
            short4v pk;
            #pragma unroll
            for (int i = 0; i < 4; i++)
                pk[i] = f2bf(ot[dt][rq * 4 + i] * inv);
            int dbase = dt * 32 + 8 * rq + 4 * half;
            *(short4v*)&Pw[c * PPW + dbase] = pk;
        }
    }
    asm volatile("s_waitcnt lgkmcnt(0)" ::: "memory");
    __builtin_amdgcn_wave_barrier();
    {
        int q  = lane >> 1;
        int d0 = (lane & 1) * 32;
        short8 v0 = *(const short8*)&Pw[q * PPW + d0];
        short8 v1 = *(const short8*)&Pw[q * PPW + d0 + 8];
        short8 v2 = *(const short8*)&Pw[q * PPW + d0 + 16];
        short8 v3 = *(const short8*)&Pw[q * PPW + d0 + 24];
        ushort* op = out + (bS + qbase + w * 32 + q) * D_ + h * DH_ + d0;
        *(short8*)(op)      = v0;
        *(short8*)(op + 8)  = v1;
        *(short8*)(op + 16) = v2;
        *(short8*)(op + 24) = v3;
    }
}

// ---------------------------------------------------------------------------
// RoPE (+0.125 on q) in place on bf16 local qkv.
// ---------------------------------------------------------------------------
__global__ __launch_bounds__(256) void rope_kernel(ushort* __restrict__ qkv)
{
    int idx = blockIdx.x * 256 + threadIdx.x;
    int d  = idx & 31;
    int h  = (idx >> 5) & 7;
    int bs = idx >> 8;
    int pos = bs & (S_ - 1);
    float inv_freq = exp2f(-(float)d * (2.0f / 64.0f) * 13.287712379549449f);
    float ang = (float)pos * inv_freq;
    float sn, cs;
    sincosf(ang, &sn, &cs);
    ushort* base = qkv + (size_t)bs * TRD + h * DH_;
    float q1 = bf2f(base[d]), q2 = bf2f(base[d + 32]);
    base[d]      = (ushort)f2bf((q1 * cs - q2 * sn) * 0.125f);
    base[d + 32] = (ushort)f2bf((q2 * cs + q1 * sn) * 0.125f);
    ushort* kb = base + D_;
    float k1 = bf2f(kb[d]), k2 = bf2f(kb[d + 32]);
    kb[d]      = (ushort)f2bf(k1 * cs - k2 * sn);
    kb[d + 32] = (ushort)f2bf(k2 * cs + k1 * sn);
}

// ---------------------------------------------------------------------------
extern "C" void kernel_launch(void* const* d_in, const int* in_sizes, int n_in,
                              void* d_out, int out_size, void* d_ws, size_t ws_size,
                              hipStream_t stream)
{
    (void)in_sizes; (void)n_in; (void)out_size; (void)ws_size;
    const float* src        = (const float*)d_in[0];
    const float* in_proj_w  = (const float*)d_in[1];
    const float* in_proj_b  = (const float*)d_in[2];
    const float* out_proj_w = (const float*)d_in[3];
    const float* out_proj_b = (const float*)d_in[4];
    const float* ln_g       = (const float*)d_in[5];
    const float* ln_b       = (const float*)d_in[6];
    const float* qkv_w      = (const float*)d_in[7];
    const float* to_out_w   = (const float*)d_in[8];
    const float* gl_w       = (const float*)d_in[9];
    const float* gl_b       = (const float*)d_in[10];
    const float* norm1_g    = (const float*)d_in[11];
    const float* norm1_b    = (const float*)d_in[12];
    const float* lin1_w     = (const float*)d_in[13];
    const float* lin1_b     = (const float*)d_in[14];
    const float* lin2_w     = (const float*)d_in[15];
    const float* lin2_b     = (const float*)d_in[16];
    const float* norm2_g    = (const float*)d_in[17];
    const float* norm2_b    = (const float*)d_in[18];
    float* out = (float*)d_out;

    ushort* ws16   = (ushort*)d_ws;
    ushort* src_bf = ws16;
    ushort* wi_bf  = src_bf + (size_t)MR_ * D_;
    ushort* wq_bf  = wi_bf  + TRD * D_;
    ushort* wo_bf  = wq_bf  + TRD * D_;
    ushort* wt_bf  = wo_bf  + D_ * D_;
    ushort* wg_bf  = wt_bf  + D_ * D_;
    ushort* w1_bf  = wg_bf  + D_ * 2 * D_;
    ushort* w2_bf  = w1_bf  + FF_ * D_;
    ushort* buf1   = w2_bf  + D_ * FF_;             // 8192*512
    ushort* h1b    = buf1   + (size_t)MR_ * D_;     // 8192*512
    ushort* buf0   = h1b    + (size_t)MR_ * D_;     // 8192*1536 (qkv)
    ushort* buf2   = buf0   + (size_t)MR_ * TRD;    // 8192*1024 (cat)
    ushort* vtg    = buf2   + (size_t)MR_ * 2 * D_; // 8192*512  V^T global
    ushort* vtl    = vtg    + (size_t)MR_ * D_;     // 8192*512  V^T local
    ushort* ff1    = buf0;                          // overlays buf0+buf2

    dim3 blk256(256), blk128(128);

    CvtJobs jobs;
    jobs.s[0] = src;        jobs.d[0] = src_bf; jobs.n[0] = MR_ * D_;
    jobs.s[1] = in_proj_w;  jobs.d[1] = wi_bf;  jobs.n[1] = TRD * D_;
    jobs.s[2] = qkv_w;      jobs.d[2] = wq_bf;  jobs.n[2] = TRD * D_;
    jobs.s[3] = out_proj_w; jobs.d[3] = wo_bf;  jobs.n[3] = D_ * D_;
    jobs.s[4] = to_out_w;   jobs.d[4] = wt_bf;  jobs.n[4] = D_ * D_;
    jobs.s[5] = gl_w;       jobs.d[5] = wg_bf;  jobs.n[5] = D_ * 2 * D_;
    jobs.s[6] = lin1_w;     jobs.d[6] = w1_bf;  jobs.n[6] = FF_ * D_;
    jobs.s[7] = lin2_w;     jobs.d[7] = w2_bf;  jobs.n[7] = D_ * FF_;
    cvt_kernel<<<dim3((MR_ * D_ / 4 + 255) / 256), blk256, 0, stream>>>(jobs);

    // 1. qkv_g = src @ in_proj^T + b                              -> buf0
    gemm_bf16_kernel<<<dim3(TRD / 128, MR_ / 128), blk256, 0, stream>>>(
        src_bf, D_, wi_bf, in_proj_b, buf0, TRD, D_, 0);
    // 1b. V^T for global attention                                -> vtg
    transpose_v_kernel<<<dim3(S_ / 64, B_ * H_), blk256, 0, stream>>>(buf0, vtg);
    // 2. global attention                                         -> buf1
    attn_kernel<0><<<dim3(S_ / 64, B_ * H_), blk128, 0, stream>>>(buf0, vtg, buf1);
    // 3. go = attn @ out_proj^T + b                               -> cat[:, :512]
    gemm_bf16_kernel<<<dim3(D_ / 128, MR_ / 128), blk256, 0, stream>>>(
        buf1, D_, wo_bf, out_proj_b, buf2, 2 * D_, D_, 0);
    // 4. x = LN(src)                                              -> buf1
    addln_kernel<float, float, ushort><<<dim3(MR_ / 4), blk256, 0, stream>>>(
        src, (const float*)nullptr, ln_g, ln_b, buf1);
    // 5. qkv_l = x @ qkv_w^T                                      -> buf0
    gemm_bf16_kernel<<<dim3(TRD / 128, MR_ / 128), blk256, 0, stream>>>(
        buf1, D_, wq_bf, nullptr, buf0, TRD, D_, 0);
    // 5b. V^T for local attention                                 -> vtl
    transpose_v_kernel<<<dim3(S_ / 64, B_ * H_), blk256, 0, stream>>>(buf0, vtl);
    // 6. RoPE + q-scale in place
    rope_kernel<<<dim3((B_ * S_ * H_ * 32) / 256), blk256, 0, stream>>>(buf0);
    // 7. local windowed attention                                 -> buf1
    attn_kernel<1><<<dim3(S_ / 64, B_ * H_), blk128, 0, stream>>>(buf0, vtl, buf1);
    // 8. lo = lo_pre @ to_out^T                                   -> cat[:, 512:]
    gemm_bf16_kernel<<<dim3(D_ / 128, MR_ / 128), blk256, 0, stream>>>(
        buf1, D_, wt_bf, nullptr, buf2 + D_, 2 * D_, D_, 0);
    // 9. src2 = cat @ gl_w^T + b  (K=1024)                        -> buf1
    gemm_bf16_kernel<<<dim3(D_ / 128, MR_ / 128), blk256, 0, stream>>>(
        buf2, 2 * D_, wg_bf, gl_b, buf1, D_, 2 * D_, 0);
    // 10. h1 = LN(src + src2)                                     -> h1b
    addln_kernel<float, ushort, ushort><<<dim3(MR_ / 4), blk256, 0, stream>>>(
        src, buf1, norm1_g, norm1_b, h1b);
    // 11. ff1 = relu(h1 @ lin1^T + b)                             -> ff1
    gemm_bf16_kernel<<<dim3(FF_ / 128, MR_ / 128), blk256, 0, stream>>>(
        h1b, D_, w1_bf, lin1_b, ff1, FF_, D_, 1);
    // 12. ff2 = ff1 @ lin2^T + b  (K=2048)                        -> buf1
    gemm_bf16_kernel<<<dim3(D_ / 128, MR_ / 128), blk256, 0, stream>>>(
        ff1, FF_, w2_bf, lin2_b, buf1, D_, FF_, 0);
    // 13. out = LN(h1 + ff2)                                      -> d_out (fp32)
    addln_kernel<ushort, ushort, float><<<dim3(MR_ / 4), blk256, 0, stream>>>(
        h1b, buf1, norm2_g, norm2_b, out);
}

// Round 6
// 440.163 us; speedup vs baseline: 5.6721x; 1.0507x over previous
//
#include <hip/hip_runtime.h>
#include <math.h>

#define B_  4
#define S_  2048
#define D_  512
#define H_  8
#define FF_ 2048
#define W_  128
#define DH_ 64
#define TRD (3*D_)   // 1536
#define MR_ (B_*S_)  // 8192 rows
#define LDO_ 1024    // concat buffer row stride

typedef __attribute__((ext_vector_type(8)))  short short8;
typedef __attribute__((ext_vector_type(4)))  float f32x4;
typedef __attribute__((ext_vector_type(16))) float f32x16;

__device__ __forceinline__ short f2bf(float f) {
    unsigned u = __float_as_uint(f);
    unsigned r = (u + 0x7fff + ((u >> 16) & 1)) >> 16;   // RNE
    return (short)r;
}
__device__ __forceinline__ float bf2f(ushort u) {
    return __uint_as_float(((unsigned)u) << 16);
}
// pack two fp32 -> one dword of two bf16 (truncation) with a single v_perm
__device__ __forceinline__ unsigned pack_bf_trunc(float f0, float f1) {
    return __builtin_amdgcn_perm(__float_as_uint(f1), __float_as_uint(f0), 0x07060302u);
}
__device__ __forceinline__ void gload_lds16(const ushort* g, short* l) {
    __builtin_amdgcn_global_load_lds(
        (const __attribute__((address_space(1))) void*)g,
        (__attribute__((address_space(3))) void*)l, 16, 0, 0);
}

// ---------------------------------------------------------------------------
// Fused fp32 -> bf16 conversion for src + 7 weight tensors.
// ---------------------------------------------------------------------------
struct CvtJobs { const float* s[8]; ushort* d[8]; int n[8]; };

__global__ __launch_bounds__(256) void cvt_kernel(CvtJobs jobs)
{
    int i4 = (blockIdx.x * 256 + threadIdx.x) * 4;
    #pragma unroll
    for (int j = 0; j < 8; j++) {
        if (i4 < jobs.n[j]) {
            float4 v = *(const float4*)(jobs.s[j] + i4);
            ushort4 o;
            o.x = (ushort)f2bf(v.x); o.y = (ushort)f2bf(v.y);
            o.z = (ushort)f2bf(v.z); o.w = (ushort)f2bf(v.w);
            *(ushort4*)(jobs.d[j] + i4) = o;
        }
    }
}

// ---------------------------------------------------------------------------
// bf16 MFMA GEMM, 128(M)x64(N) tile, BK=64, global_load_lds + XOR swizzle.
// Block 256 = 4 waves in 2x2 (wave: 64 rows x 32 cols = 4x2 16x16x32 tiles).
// Doubles grid size vs 128x128 for small-N shapes (occupancy).
// ---------------------------------------------------------------------------
__global__ __launch_bounds__(256) void gemm_bf16_kernel(
    const ushort* __restrict__ A, int lda,
    const ushort* __restrict__ Wt,     // [N][K] row-major
    const float* __restrict__ bias,
    ushort* __restrict__ C, int ldc,
    int K, int relu)
{
    __shared__ short As[128 * 64];
    __shared__ short Bs[64 * 64];
    const int tid  = threadIdx.x;
    const int w    = tid >> 6;
    const int lane = tid & 63;
    const int quad = lane >> 4;
    const int x    = lane & 15;
    const int wr = w >> 1, wc = w & 1;
    const int bm = blockIdx.y * 128;
    const int bn = blockIdx.x * 64;

    const int srow = (lane >> 3);
    const int scol = ((lane & 7) ^ (lane >> 3)) * 8;   // swizzled source colgroup

    f32x4 acc[4][2];
    #pragma unroll
    for (int i = 0; i < 4; i++)
        #pragma unroll
        for (int j = 0; j < 2; j++) acc[i][j] = (f32x4)0.f;

    for (int k0 = 0; k0 < K; k0 += 64) {
        __syncthreads();
        #pragma unroll
        for (int c = 0; c < 4; c++) {   // A rows: wave w stages [w*32, +32)
            const ushort* ga = A + (size_t)(bm + w * 32 + c * 8 + srow) * lda + k0 + scol;
            gload_lds16(ga, &As[(w * 32 + c * 8) * 64]);
        }
        #pragma unroll
        for (int c = 0; c < 2; c++) {   // B rows: wave w stages [w*16, +16)
            const ushort* gb = Wt + (size_t)(bn + w * 16 + c * 8 + srow) * K + k0 + scol;
            gload_lds16(gb, &Bs[(w * 16 + c * 8) * 64]);
        }
        __syncthreads();

        #pragma unroll
        for (int kc = 0; kc < 2; kc++) {
            short8 af[4], bf[2];
            int pcg = (kc * 4 + quad) ^ (x & 7);
            #pragma unroll
            for (int i = 0; i < 4; i++)
                af[i] = *(const short8*)&As[(wr * 64 + i * 16 + x) * 64 + pcg * 8];
            #pragma unroll
            for (int j = 0; j < 2; j++)
                bf[j] = *(const short8*)&Bs[(wc * 32 + j * 16 + x) * 64 + pcg * 8];
            #pragma unroll
            for (int i = 0; i < 4; i++)
                #pragma unroll
                for (int j = 0; j < 2; j++)
                    acc[i][j] = __builtin_amdgcn_mfma_f32_16x16x32_bf16(af[i], bf[j], acc[i][j], 0, 0, 0);
        }
    }

    #pragma unroll
    for (int i = 0; i < 4; i++) {
        #pragma unroll
        for (int r = 0; r < 4; r++) {
            size_t row = (size_t)(bm + wr * 64 + i * 16 + quad * 4 + r);
            #pragma unroll
            for (int j = 0; j < 2; j++) {
                int col = bn + wc * 32 + j * 16 + x;
                float v = acc[i][j][r] + (bias ? bias[col] : 0.f);
                if (relu) v = v > 0.f ? v : 0.f;
                C[row * ldc + col] = (ushort)f2bf(v);
            }
        }
    }
}

// ---------------------------------------------------------------------------
// LayerNorm over D=512, wave per row; templated dtypes.
// ---------------------------------------------------------------------------
__device__ __forceinline__ float wave_sum64(float v) {
    #pragma unroll
    for (int off = 32; off > 0; off >>= 1) v += __shfl_xor(v, off, 64);
    return v;
}
__device__ __forceinline__ void load8(const float* p, float* v) {
    *(float4*)&v[0] = *(const float4*)p;
    *(float4*)&v[4] = *(const float4*)(p + 4);
}
__device__ __forceinline__ void load8(const ushort* p, float* v) {
    short8 s = *(const short8*)p;
    #pragma unroll
    for (int i = 0; i < 8; i++) v[i] = bf2f((ushort)s[i]);
}
__device__ __forceinline__ void store8(float* p, const float* v) {
    *(float4*)p       = make_float4(v[0], v[1], v[2], v[3]);
    *(float4*)(p + 4) = make_float4(v[4], v[5], v[6], v[7]);
}
__device__ __forceinline__ void store8(ushort* p, const float* v) {
    short8 s;
    #pragma unroll
    for (int i = 0; i < 8; i++) s[i] = f2bf(v[i]);
    *(short8*)p = s;
}

template <typename TA, typename TB, typename TO>
__global__ __launch_bounds__(256) void addln_kernel(
    const TA* __restrict__ a, const TB* __restrict__ b,
    const float* __restrict__ g, const float* __restrict__ be,
    TO* __restrict__ out)
{
    const int lane = threadIdx.x & 63;
    const int row  = blockIdx.x * 4 + (threadIdx.x >> 6);
    const size_t base = (size_t)row * D_ + lane * 8;
    float v[8];
    load8(a + base, v);
    if (b) {
        float wv[8];
        load8(b + base, wv);
        #pragma unroll
        for (int i = 0; i < 8; i++) v[i] += wv[i];
    }
    float s = 0.f;
    #pragma unroll
    for (int i = 0; i < 8; i++) s += v[i];
    float mean = wave_sum64(s) * (1.0f / 512.0f);
    float vs = 0.f;
    #pragma unroll
    for (int i = 0; i < 8; i++) { float d = v[i] - mean; vs += d * d; }
    float var = wave_sum64(vs) * (1.0f / 512.0f);
    float r = rsqrtf(var + 1e-5f);
    const int c = lane * 8;
    float t[8];
    #pragma unroll
    for (int i = 0; i < 8; i++) t[i] = (v[i] - mean) * r * g[c + i] + be[c + i];
    store8(out + base, t);
}

// ---------------------------------------------------------------------------
// Transpose V third of qkv into VT[b][h][d][s] (bf16). Grid (S/64, B*H).
// ---------------------------------------------------------------------------
__global__ __launch_bounds__(256) void transpose_v_kernel(
    const ushort* __restrict__ qkv, ushort* __restrict__ vt)
{
    __shared__ ushort T[64][72];
    const int t  = threadIdx.x;
    const int s0 = blockIdx.x * 64;
    const int bh = blockIdx.y;
    const int b = bh >> 3, h = bh & 7;
    {
        int row = t >> 2, col = (t & 3) * 16;
        const ushort* src = qkv + ((size_t)(b * S_) + s0 + row) * TRD + 2 * D_ + h * DH_ + col;
        *(short8*)&T[row][col]     = *(const short8*)src;
        *(short8*)&T[row][col + 8] = *(const short8*)(src + 8);
    }
    __syncthreads();
    {
        int d = t >> 2, sc = (t & 3) * 16;
        ushort tmp[16];
        #pragma unroll
        for (int k = 0; k < 16; k++) tmp[k] = T[sc + k][d];
        ushort* dst = vt + ((size_t)bh * DH_ + d) * S_ + s0 + sc;
        *(short8*)dst       = *(const short8*)&tmp[0];
        *(short8*)(dst + 8) = *(const short8*)&tmp[8];
    }
}

// ---------------------------------------------------------------------------
// Generic bf16 512x512 transpose (for weight prep). Grid (8,8).
// ---------------------------------------------------------------------------
__global__ __launch_bounds__(256) void transpose512_kernel(
    const ushort* __restrict__ in, ushort* __restrict__ out)
{
    __shared__ ushort T[64][72];
    const int t  = threadIdx.x;
    const int r0 = blockIdx.y * 64, c0 = blockIdx.x * 64;
    {
        int row = t >> 2, col = (t & 3) * 16;
        const ushort* s = in + (size_t)(r0 + row) * 512 + c0 + col;
        *(short8*)&T[row][col]     = *(const short8*)s;
        *(short8*)&T[row][col + 8] = *(const short8*)(s + 8);
    }
    __syncthreads();
    {
        int d = t >> 2, sc = (t & 3) * 16;
        ushort tmp[16];
        #pragma unroll
        for (int k = 0; k < 16; k++) tmp[k] = T[sc + k][d];
        ushort* dptr = out + (size_t)(c0 + d) * 512 + r0 + sc;
        *(short8*)dptr       = *(const short8*)&tmp[0];
        *(short8*)(dptr + 8) = *(const short8*)&tmp[8];
    }
}

// ---------------------------------------------------------------------------
// bfuse[n] = sum_m gl_w[n][m] * out_proj_b[m] + gl_b[n]  (fp32). Wave/row.
// ---------------------------------------------------------------------------
__global__ __launch_bounds__(256) void fuse_bias_kernel(
    const float* __restrict__ gl_w, const float* __restrict__ opb,
    const float* __restrict__ gl_b, float* __restrict__ bf)
{
    const int lane = threadIdx.x & 63;
    const int row  = blockIdx.x * 4 + (threadIdx.x >> 6);
    float s = 0.f;
    #pragma unroll
    for (int i = 0; i < 8; i++) {
        int m = lane * 8 + i;
        s += gl_w[(size_t)row * 1024 + m] * opb[m];
    }
    s = wave_sum64(s);
    if (lane == 0) bf[row] = s + gl_b[row];
}

// ---------------------------------------------------------------------------
// Attention core v2: 32x32x16 MFMA, S^T layout (lane = q-column, regs = keys),
// no-max softmax (scores bounded), register-resident P via perm/shfl/cndmask,
// in-block split-K (4 waves: wave = (ks = w>>1 key-chunk, qh = w&1 q-half)).
// Partial O / l are additive (no max rescale) -> combine once via LDS.
// 32x32 layouts (m74/m101): A/B[row=lane&31][k=(lane>>5)*8+j];
// C/D col=lane&31, row=(reg&3)+8*(reg>>2)+4*(lane>>5).
// ---------------------------------------------------------------------------
template <int LOCAL>
__global__ __launch_bounds__(256) void attn_kernel(
    const ushort* __restrict__ qkv, const ushort* __restrict__ vt,
    ushort* __restrict__ outp)
{
    __shared__ short KsS[2][64 * 64];   // [pair][key][d], XOR-swizzled
    __shared__ short VtS[2][64 * 64];   // [pair][d][key], XOR-swizzled
    __shared__ float Lw[4][32];

    const int tid  = threadIdx.x;
    const int w    = tid >> 6;
    const int lane = tid & 63;
    const int hl   = lane >> 5;
    const int c    = lane & 31;
    const int ks   = w >> 1;
    const int qh   = w & 1;
    const int bh = blockIdx.y;
    const int b = bh >> 3, h = bh & 7;
    const int qbase = blockIdx.x * 64;
    const int q0 = qbase + qh * 32;       // my wave's 32 q-rows
    const size_t bS = (size_t)b * S_;
    const size_t vbase = (size_t)bh * DH_;

    // Q fragments (B-operand layout), global folds 0.125 (local pre-scaled)
    short8 aq[4];
    {
        const ushort* qp = qkv + (bS + q0 + c) * TRD + h * DH_;
        #pragma unroll
        for (int kc = 0; kc < 4; kc++) {
            short8 raw = *(const short8*)(qp + kc * 16 + hl * 8);
            if (LOCAL) aq[kc] = raw;
            else {
                #pragma unroll
                for (int j = 0; j < 8; j++) aq[kc][j] = f2bf(bf2f((ushort)raw[j]) * 0.125f);
            }
        }
    }

    f32x16 ot[2];
    ot[0] = (f32x16)0.f; ot[1] = (f32x16)0.f;
    float lp = 0.f;

    const int NIT = LOCAL ? 2 : (S_ / 64 / 2);
    for (int it = 0; it < NIT; it++) {
        const int tile  = LOCAL ? (ks * 2 + it) : (ks * NIT + it);
        const int kbase = LOCAL ? ((qbase >> 7) * 128 - 128 + tile * 64) : tile * 64;
        const bool active = !LOCAL || (kbase >= 0 && kbase <= qbase + 63);
        __syncthreads();   // prior reads of my pair's buffers done
        if (active) {
            #pragma unroll
            for (int cc = 0; cc < 4; cc++) {
                int row = qh * 32 + cc * 8 + (lane >> 3);
                int cg  = (lane & 7) ^ (lane >> 3);
                gload_lds16(qkv + (bS + kbase + row) * TRD + D_ + h * DH_ + cg * 8,
                            &KsS[ks][(qh * 32 + cc * 8) * 64]);
                gload_lds16(vt + (vbase + row) * S_ + kbase + cg * 8,
                            &VtS[ks][(qh * 32 + cc * 8) * 64]);
            }
        }
        __syncthreads();   // DMA drained
        if (!active) continue;   // (after both barriers -> counts match)
        const bool diag = LOCAL && (kbase == qbase);

        // S^T = K Q^T : D[key][q], A = K-frags from LDS, B = Q regs
        f32x16 e0 = (f32x16)0.f, e1 = (f32x16)0.f;
        #pragma unroll
        for (int kc = 0; kc < 4; kc++) {
            int pcg = (kc * 2 + hl) ^ (c & 7);       // (32+c)&7 == c&7
            short8 ak0 = *(const short8*)&KsS[ks][c * 64 + pcg * 8];
            e0 = __builtin_amdgcn_mfma_f32_32x32x16_bf16(ak0, aq[kc], e0, 0, 0, 0);
            short8 ak1 = *(const short8*)&KsS[ks][(32 + c) * 64 + pcg * 8];
            e1 = __builtin_amdgcn_mfma_f32_32x32x16_bf16(ak1, aq[kc], e1, 0, 0, 0);
        }

        // exp (no max: |s| small) + mask + per-lane l partial + bf16 pack
        unsigned pk[2][8];
        const int qi = q0 + c;
        #pragma unroll
        for (int mt = 0; mt < 2; mt++) {
            f32x16& e = mt ? e1 : e0;
            #pragma unroll
            for (int r = 0; r < 16; r++) {
                float p = __expf(e[r]);
                if (diag) {
                    int key = kbase + mt * 32 + (r & 3) + 8 * (r >> 2) + 4 * hl;
                    if (key > qi) p = 0.f;
                }
                e[r] = p;
                lp += p;
            }
            #pragma unroll
            for (int g = 0; g < 8; g++)
                pk[mt][g] = pack_bf_trunc(e[2 * g], e[2 * g + 1]);
        }

        // O^T += V^T P^T : B-frag (P) built from regs via shfl_xor(32)+select
        #pragma unroll
        for (int kc = 0; kc < 4; kc++) {
            const int mt = kc >> 1, kp = kc & 1;
            unsigned m0 = pk[mt][4 * kp + 0], m1 = pk[mt][4 * kp + 1];
            unsigned m2 = pk[mt][4 * kp + 2], m3 = pk[mt][4 * kp + 3];
            unsigned s0 = (unsigned)__shfl_xor((int)m0, 32, 64);
            unsigned s1 = (unsigned)__shfl_xor((int)m1, 32, 64);
            unsigned s2 = (unsigned)__shfl_xor((int)m2, 32, 64);
            unsigned s3 = (unsigned)__shfl_xor((int)m3, 32, 64);
            uint4 fd;
            fd.x = hl ? s2 : m0;   // keys j0-1 (hl0-holder regs)
            fd.y = hl ? s3 : m1;   // keys j2-3
            fd.z = hl ? m2 : s0;   // keys j4-5 (hl1-holder regs)
            fd.w = hl ? m3 : s1;   // keys j6-7
            short8 bp = *(short8*)&fd;
            #pragma unroll
            for (int dt = 0; dt < 2; dt++) {
                int row = dt * 32 + c;
                int pcg = (kc * 2 + hl) ^ (c & 7);
                short8 av = *(const short8*)&VtS[ks][row * 64 + pcg * 8];
                ot[dt] = __builtin_amdgcn_mfma_f32_32x32x16_bf16(av, bp, ot[dt], 0, 0, 0);
            }
        }
    }

    // l for q=c over my chunk: my-half keys + partner-half keys
    lp += __shfl_xor(lp, 32, 64);
    if (hl == 0) Lw[w][c] = lp;
    __syncthreads();   // all tile reads done; Lw visible; staging bufs now free

    // cross-pair combine: waves 2,3 dump O^T partials into (dead) KsS region
    float* scr = (float*)&KsS[0][0];   // 16 KB = 2 x 2048 floats
    if (w >= 2) {
        float* dst = scr + (w - 2) * 2048;
        #pragma unroll
        for (int dt = 0; dt < 2; dt++)
            #pragma unroll
            for (int r = 0; r < 16; r++)
                dst[(dt * 16 + r) * 64 + lane] = ot[dt][r];
    }
    __syncthreads();
    if (w < 2) {
        const float* srcp = scr + w * 2048;
        #pragma unroll
        for (int dt = 0; dt < 2; dt++)
            #pragma unroll
            for (int r = 0; r < 16; r++)
                ot[dt][r] += srcp[(dt * 16 + r) * 64 + lane];
        float inv = 1.0f / (Lw[w][c] + Lw[w + 2][c]);

        // O^T -> bf16 transpose staging in (dead) VtS region, pitch 72
        short* tr = (short*)&VtS[0][0] + w * 2304;
        #pragma unroll
        for (int dt = 0; dt < 2; dt++)
            #pragma unroll
            for (int rq = 0; rq < 4; rq++) {
                uint2 pkv;
                pkv.x = pack_bf_trunc(ot[dt][rq * 4 + 0] * inv, ot[dt][rq * 4 + 1] * inv);
                pkv.y = pack_bf_trunc(ot[dt][rq * 4 + 2] * inv, ot[dt][rq * 4 + 3] * inv);
                *(uint2*)&tr[c * 72 + dt * 32 + 8 * rq + 4 * hl] = pkv;
            }
        asm volatile("s_waitcnt lgkmcnt(0)" ::: "memory");
        __builtin_amdgcn_wave_barrier();
        {
            int q  = lane >> 1;
            int d0 = (lane & 1) * 32;
            short8 v0 = *(const short8*)&tr[q * 72 + d0];
            short8 v1 = *(const short8*)&tr[q * 72 + d0 + 8];
            short8 v2 = *(const short8*)&tr[q * 72 + d0 + 16];
            short8 v3 = *(const short8*)&tr[q * 72 + d0 + 24];
            ushort* op = outp + (bS + q0 + q) * LDO_ + h * DH_ + d0;
            *(short8*)(op)      = v0;
            *(short8*)(op + 8)  = v1;
            *(short8*)(op + 16) = v2;
            *(short8*)(op + 24) = v3;
        }
    }
}

// ---------------------------------------------------------------------------
// RoPE (+0.125 on q) in place on bf16 local qkv.
// ---------------------------------------------------------------------------
__global__ __launch_bounds__(256) void rope_kernel(ushort* __restrict__ qkv)
{
    int idx = blockIdx.x * 256 + threadIdx.x;
    int d  = idx & 31;
    int h  = (idx >> 5) & 7;
    int bs = idx >> 8;
    int pos = bs & (S_ - 1);
    float inv_freq = exp2f(-(float)d * (2.0f / 64.0f) * 13.287712379549449f);
    float ang = (float)pos * inv_freq;
    float sn, cs;
    sincosf(ang, &sn, &cs);
    ushort* base = qkv + (size_t)bs * TRD + h * DH_;
    float q1 = bf2f(base[d]), q2 = bf2f(base[d + 32]);
    base[d]      = (ushort)f2bf((q1 * cs - q2 * sn) * 0.125f);
    base[d + 32] = (ushort)f2bf((q2 * cs + q1 * sn) * 0.125f);
    ushort* kb = base + D_;
    float k1 = bf2f(kb[d]), k2 = bf2f(kb[d + 32]);
    kb[d]      = (ushort)f2bf(k1 * cs - k2 * sn);
    kb[d + 32] = (ushort)f2bf(k2 * cs + k1 * sn);
}

// ---------------------------------------------------------------------------
extern "C" void kernel_launch(void* const* d_in, const int* in_sizes, int n_in,
                              void* d_out, int out_size, void* d_ws, size_t ws_size,
                              hipStream_t stream)
{
    (void)in_sizes; (void)n_in; (void)out_size; (void)ws_size;
    const float* src        = (const float*)d_in[0];
    const float* in_proj_w  = (const float*)d_in[1];
    const float* in_proj_b  = (const float*)d_in[2];
    const float* out_proj_w = (const float*)d_in[3];
    const float* out_proj_b = (const float*)d_in[4];
    const float* ln_g       = (const float*)d_in[5];
    const float* ln_b       = (const float*)d_in[6];
    const float* qkv_w      = (const float*)d_in[7];
    const float* to_out_w   = (const float*)d_in[8];
    const float* gl_w       = (const float*)d_in[9];
    const float* gl_b       = (const float*)d_in[10];
    const float* norm1_g    = (const float*)d_in[11];
    const float* norm1_b    = (const float*)d_in[12];
    const float* lin1_w     = (const float*)d_in[13];
    const float* lin1_b     = (const float*)d_in[14];
    const float* lin2_w     = (const float*)d_in[15];
    const float* lin2_b     = (const float*)d_in[16];
    const float* norm2_g    = (const float*)d_in[17];
    const float* norm2_b    = (const float*)d_in[18];
    float* out = (float*)d_out;

    // --- workspace layout (ushorts), ~87 MB ---
    ushort* ws16   = (ushort*)d_ws;
    ushort* src_bf = ws16;                          // 8192*512
    ushort* wi_bf  = src_bf + (size_t)MR_ * D_;     // 1536*512
    ushort* wq_bf  = wi_bf  + TRD * D_;             // 1536*512
    ushort* wo_bf  = wq_bf  + TRD * D_;             // 512*512
    ushort* wt_bf  = wo_bf  + D_ * D_;              // 512*512
    ushort* wg_bf  = wt_bf  + D_ * D_;              // 512*1024
    ushort* w1_bf  = wg_bf  + D_ * 2 * D_;          // 2048*512
    ushort* w2_bf  = w1_bf  + FF_ * D_;             // 512*2048
    ushort* opwT   = w2_bf  + D_ * FF_;             // 512*512
    ushort* towT   = opwT   + D_ * D_;              // 512*512
    ushort* wcat   = towT   + D_ * D_;              // 512*1024 fused weight
    ushort* buf1   = wcat   + D_ * 2 * D_;          // 8192*512  (x / src2 / ff2)
    ushort* h1b    = buf1   + (size_t)MR_ * D_;     // 8192*512
    ushort* buf0   = h1b    + (size_t)MR_ * D_;     // 8192*1536 (qkv)
    ushort* cat    = buf0   + (size_t)MR_ * TRD;    // 8192*1024 [go_pre|lo_pre]
    ushort* vtb    = cat    + (size_t)MR_ * 2 * D_; // 8192*512  V^T (shared g/l)
    float*  bfuse  = (float*)(vtb + (size_t)MR_ * D_); // 512 fp32
    ushort* ff1    = buf0;                          // overlays buf0+cat

    dim3 blk256(256);

    // 0. fp32 -> bf16 conversions
    CvtJobs jobs;
    jobs.s[0] = src;        jobs.d[0] = src_bf; jobs.n[0] = MR_ * D_;
    jobs.s[1] = in_proj_w;  jobs.d[1] = wi_bf;  jobs.n[1] = TRD * D_;
    jobs.s[2] = qkv_w;      jobs.d[2] = wq_bf;  jobs.n[2] = TRD * D_;
    jobs.s[3] = out_proj_w; jobs.d[3] = wo_bf;  jobs.n[3] = D_ * D_;
    jobs.s[4] = to_out_w;   jobs.d[4] = wt_bf;  jobs.n[4] = D_ * D_;
    jobs.s[5] = gl_w;       jobs.d[5] = wg_bf;  jobs.n[5] = D_ * 2 * D_;
    jobs.s[6] = lin1_w;     jobs.d[6] = w1_bf;  jobs.n[6] = FF_ * D_;
    jobs.s[7] = lin2_w;     jobs.d[7] = w2_bf;  jobs.n[7] = D_ * FF_;
    cvt_kernel<<<dim3((MR_ * D_ / 4 + 255) / 256), blk256, 0, stream>>>(jobs);

    // 0b. weight prep: Wc1 = G1 @ OPW^T-fold, Wc2 = G2 @ TOW-fold, bias fold
    transpose512_kernel<<<dim3(8, 8), blk256, 0, stream>>>(wo_bf, opwT);
    transpose512_kernel<<<dim3(8, 8), blk256, 0, stream>>>(wt_bf, towT);
    gemm_bf16_kernel<<<dim3(D_ / 64, D_ / 128), blk256, 0, stream>>>(
        wg_bf, 2 * D_, opwT, nullptr, wcat, 2 * D_, D_, 0);          // Wc1 -> wcat[:, :512]
    gemm_bf16_kernel<<<dim3(D_ / 64, D_ / 128), blk256, 0, stream>>>(
        wg_bf + D_, 2 * D_, towT, nullptr, wcat + D_, 2 * D_, D_, 0); // Wc2 -> wcat[:, 512:]
    fuse_bias_kernel<<<dim3(D_ / 4), blk256, 0, stream>>>(gl_w, out_proj_b, gl_b, bfuse);

    // 1. qkv_g = src @ in_proj^T + b                              -> buf0
    gemm_bf16_kernel<<<dim3(TRD / 64, MR_ / 128), blk256, 0, stream>>>(
        src_bf, D_, wi_bf, in_proj_b, buf0, TRD, D_, 0);
    // 1b. V^T for global attention                                -> vtb
    transpose_v_kernel<<<dim3(S_ / 64, B_ * H_), blk256, 0, stream>>>(buf0, vtb);
    // 2. global attention                                         -> cat[:, :512]
    attn_kernel<0><<<dim3(S_ / 64, B_ * H_), blk256, 0, stream>>>(buf0, vtb, cat);
    // 3. x = LN(src)                                              -> buf1
    addln_kernel<float, float, ushort><<<dim3(MR_ / 4), blk256, 0, stream>>>(
        src, (const float*)nullptr, ln_g, ln_b, buf1);
    // 4. qkv_l = x @ qkv_w^T                                      -> buf0
    gemm_bf16_kernel<<<dim3(TRD / 64, MR_ / 128), blk256, 0, stream>>>(
        buf1, D_, wq_bf, nullptr, buf0, TRD, D_, 0);
    // 4b. V^T for local attention                                 -> vtb
    transpose_v_kernel<<<dim3(S_ / 64, B_ * H_), blk256, 0, stream>>>(buf0, vtb);
    // 5. RoPE + q-scale in place (q,k only)
    rope_kernel<<<dim3((B_ * S_ * H_ * 32) / 256), blk256, 0, stream>>>(buf0);
    // 6. local windowed attention                                 -> cat[:, 512:]
    attn_kernel<1><<<dim3(S_ / 64, B_ * H_), blk256, 0, stream>>>(buf0, vtb, cat + D_);
    // 7. src2 = cat @ wcat^T + bfuse   (K=1024, fuses out_proj/to_out/gl)
    gemm_bf16_kernel<<<dim3(D_ / 64, MR_ / 128), blk256, 0, stream>>>(
        cat, 2 * D_, wcat, bfuse, buf1, D_, 2 * D_, 0);
    // 8. h1 = LN(src + src2)                                      -> h1b
    addln_kernel<float, ushort, ushort><<<dim3(MR_ / 4), blk256, 0, stream>>>(
        src, buf1, norm1_g, norm1_b, h1b);
    // 9. ff1 = relu(h1 @ lin1^T + b)                              -> ff1
    gemm_bf16_kernel<<<dim3(FF_ / 64, MR_ / 128), blk256, 0, stream>>>(
        h1b, D_, w1_bf, lin1_b, ff1, FF_, D_, 1);
    // 10. ff2 = ff1 @ lin2^T + b  (K=2048)                        -> buf1
    gemm_bf16_kernel<<<dim3(D_ / 64, MR_ / 128), blk256, 0, stream>>>(
        ff1, FF_, w2_bf, lin2_b, buf1, D_, FF_, 0);
    // 11. out = LN(h1 + ff2)                                      -> d_out (fp32)
    addln_kernel<ushort, ushort, float><<<dim3(MR_ / 4), blk256, 0, stream>>>(
        h1b, buf1, norm2_g, norm2_b, out);
}

// Round 7
// 407.284 us; speedup vs baseline: 6.1300x; 1.0807x over previous
//
#include <hip/hip_runtime.h>
#include <math.h>

#define B_  4
#define S_  2048
#define D_  512
#define H_  8
#define FF_ 2048
#define W_  128
#define DH_ 64
#define TRD (3*D_)   // 1536
#define MR_ (B_*S_)  // 8192 rows
#define QKLD 1024    // q|k buffer row stride
#define SCQ 0.18033688011112042f   // 0.125 * log2(e)

typedef __attribute__((ext_vector_type(8)))  short short8;
typedef __attribute__((ext_vector_type(4)))  float f32x4;
typedef __attribute__((ext_vector_type(16))) float f32x16;

__device__ __forceinline__ short f2bf(float f) {
    unsigned u = __float_as_uint(f);
    unsigned r = (u + 0x7fff + ((u >> 16) & 1)) >> 16;   // RNE
    return (short)r;
}
__device__ __forceinline__ float bf2f(ushort u) {
    return __uint_as_float(((unsigned)u) << 16);
}
// pack two fp32 -> dword of two bf16 (truncation), low short = f0
__device__ __forceinline__ unsigned pack_bf_trunc(float f0, float f1) {
    return __builtin_amdgcn_perm(__float_as_uint(f1), __float_as_uint(f0), 0x07060302u);
}
__device__ __forceinline__ void gload_lds16(const ushort* g, short* l) {
    __builtin_amdgcn_global_load_lds(
        (const __attribute__((address_space(1))) void*)g,
        (__attribute__((address_space(3))) void*)l, 16, 0, 0);
}

// ---------------------------------------------------------------------------
// Fused fp32 -> bf16 conversion for src + 7 weight tensors.
// ---------------------------------------------------------------------------
struct CvtJobs { const float* s[8]; ushort* d[8]; int n[8]; };

__global__ __launch_bounds__(256) void cvt_kernel(CvtJobs jobs)
{
    int i4 = (blockIdx.x * 256 + threadIdx.x) * 4;
    #pragma unroll
    for (int j = 0; j < 8; j++) {
        if (i4 < jobs.n[j]) {
            float4 v = *(const float4*)(jobs.s[j] + i4);
            ushort4 o;
            o.x = (ushort)f2bf(v.x); o.y = (ushort)f2bf(v.y);
            o.z = (ushort)f2bf(v.z); o.w = (ushort)f2bf(v.w);
            *(ushort4*)(jobs.d[j] + i4) = o;
        }
    }
}

// ---------------------------------------------------------------------------
// bf16 MFMA GEMM, 128(M)x64(N) tile, BK=64, global_load_lds + XOR swizzle.
// vt mode (vt != nullptr): cols < 1024 -> C (ld 1024); cols >= 1024 are the
// V third -> written ONLY transposed into vt[bh][d][s'] with s' = s bits2<->3
// swapped (the key permutation the attention PV path expects).
// ---------------------------------------------------------------------------
__global__ __launch_bounds__(256) void gemm_bf16_kernel(
    const ushort* __restrict__ A, int lda,
    const ushort* __restrict__ Wt,     // [N][K] row-major
    const float* __restrict__ bias,
    ushort* __restrict__ C, int ldc,
    ushort* __restrict__ vt,
    int K, int relu)
{
    __shared__ short As[128 * 64];
    __shared__ short Bs[64 * 64];
    const int tid  = threadIdx.x;
    const int w    = tid >> 6;
    const int lane = tid & 63;
    const int quad = lane >> 4;
    const int x    = lane & 15;
    const int wr = w >> 1, wc = w & 1;
    const int bm = blockIdx.y * 128;
    const int bn = blockIdx.x * 64;

    const int srow = (lane >> 3);
    const int scol = ((lane & 7) ^ (lane >> 3)) * 8;

    f32x4 acc[4][2];
    #pragma unroll
    for (int i = 0; i < 4; i++)
        #pragma unroll
        for (int j = 0; j < 2; j++) acc[i][j] = (f32x4)0.f;

    for (int k0 = 0; k0 < K; k0 += 64) {
        __syncthreads();
        #pragma unroll
        for (int c = 0; c < 4; c++) {
            const ushort* ga = A + (size_t)(bm + w * 32 + c * 8 + srow) * lda + k0 + scol;
            gload_lds16(ga, &As[(w * 32 + c * 8) * 64]);
        }
        #pragma unroll
        for (int c = 0; c < 2; c++) {
            const ushort* gb = Wt + (size_t)(bn + w * 16 + c * 8 + srow) * K + k0 + scol;
            gload_lds16(gb, &Bs[(w * 16 + c * 8) * 64]);
        }
        __syncthreads();

        #pragma unroll
        for (int kc = 0; kc < 2; kc++) {
            short8 af[4], bf[2];
            int pcg = (kc * 4 + quad) ^ (x & 7);
            #pragma unroll
            for (int i = 0; i < 4; i++)
                af[i] = *(const short8*)&As[(wr * 64 + i * 16 + x) * 64 + pcg * 8];
            #pragma unroll
            for (int j = 0; j < 2; j++)
                bf[j] = *(const short8*)&Bs[(wc * 32 + j * 16 + x) * 64 + pcg * 8];
            #pragma unroll
            for (int i = 0; i < 4; i++)
                #pragma unroll
                for (int j = 0; j < 2; j++)
                    acc[i][j] = __builtin_amdgcn_mfma_f32_16x16x32_bf16(af[i], bf[j], acc[i][j], 0, 0, 0);
        }
    }

    if (vt) {
        #pragma unroll
        for (int i = 0; i < 4; i++) {
            int rowbase = bm + wr * 64 + i * 16 + quad * 4;   // row of r=0
            #pragma unroll
            for (int j = 0; j < 2; j++) {
                int col = bn + wc * 32 + j * 16 + x;
                float bv = bias ? bias[col] : 0.f;
                if (col < 1024) {
                    #pragma unroll
                    for (int r = 0; r < 4; r++)
                        C[(size_t)(rowbase + r) * QKLD + col] = (ushort)f2bf(acc[i][j][r] + bv);
                } else {
                    int cv = col - 1024, hh = cv >> 6, dd = cv & 63;
                    int bb = rowbase >> 11, ss = rowbase & 2047;
                    int quadp = ((quad & 1) << 1) | (quad >> 1);   // swap s bits 2<->3
                    int sp = (ss & ~15) | (quadp << 2);
                    ushort4 p4;
                    p4.x = (ushort)f2bf(acc[i][j][0] + bv);
                    p4.y = (ushort)f2bf(acc[i][j][1] + bv);
                    p4.z = (ushort)f2bf(acc[i][j][2] + bv);
                    p4.w = (ushort)f2bf(acc[i][j][3] + bv);
                    *(ushort4*)(vt + ((size_t)((bb * 8 + hh) * 64 + dd)) * S_ + sp) = p4;
                }
            }
        }
    } else {
        #pragma unroll
        for (int i = 0; i < 4; i++) {
            #pragma unroll
            for (int r = 0; r < 4; r++) {
                size_t row = (size_t)(bm + wr * 64 + i * 16 + quad * 4 + r);
                #pragma unroll
                for (int j = 0; j < 2; j++) {
                    int col = bn + wc * 32 + j * 16 + x;
                    float v = acc[i][j][r] + (bias ? bias[col] : 0.f);
                    if (relu) v = v > 0.f ? v : 0.f;
                    C[row * ldc + col] = (ushort)f2bf(v);
                }
            }
        }
    }
}

// ---------------------------------------------------------------------------
// Split-K (x2) bf16 GEMM -> fp32 partials (no bias/relu). N=512 shapes.
// Grid (N/64, M/128, 2); partial z at P + z*MR_*D_.
// ---------------------------------------------------------------------------
__global__ __launch_bounds__(256) void gemm_bf16_splitk_kernel(
    const ushort* __restrict__ A, int lda,
    const ushort* __restrict__ Wt,
    float* __restrict__ P, int K)
{
    __shared__ short As[128 * 64];
    __shared__ short Bs[64 * 64];
    const int tid  = threadIdx.x;
    const int w    = tid >> 6;
    const int lane = tid & 63;
    const int quad = lane >> 4;
    const int x    = lane & 15;
    const int wr = w >> 1, wc = w & 1;
    const int bm = blockIdx.y * 128;
    const int bn = blockIdx.x * 64;
    const int kh = K >> 1;
    const int kbeg = blockIdx.z * kh;
    float* dst = P + (size_t)blockIdx.z * MR_ * D_;

    const int srow = (lane >> 3);
    const int scol = ((lane & 7) ^ (lane >> 3)) * 8;

    f32x4 acc[4][2];
    #pragma unroll
    for (int i = 0; i < 4; i++)
        #pragma unroll
        for (int j = 0; j < 2; j++) acc[i][j] = (f32x4)0.f;

    for (int k0 = kbeg; k0 < kbeg + kh; k0 += 64) {
        __syncthreads();
        #pragma unroll
        for (int c = 0; c < 4; c++) {
            const ushort* ga = A + (size_t)(bm + w * 32 + c * 8 + srow) * lda + k0 + scol;
            gload_lds16(ga, &As[(w * 32 + c * 8) * 64]);
        }
        #pragma unroll
        for (int c = 0; c < 2; c++) {
            const ushort* gb = Wt + (size_t)(bn + w * 16 + c * 8 + srow) * K + k0 + scol;
            gload_lds16(gb, &Bs[(w * 16 + c * 8) * 64]);
        }
        __syncthreads();

        #pragma unroll
        for (int kc = 0; kc < 2; kc++) {
            short8 af[4], bf[2];
            int pcg = (kc * 4 + quad) ^ (x & 7);
            #pragma unroll
            for (int i = 0; i < 4; i++)
                af[i] = *(const short8*)&As[(wr * 64 + i * 16 + x) * 64 + pcg * 8];
            #pragma unroll
            for (int j = 0; j < 2; j++)
                bf[j] = *(const short8*)&Bs[(wc * 32 + j * 16 + x) * 64 + pcg * 8];
            #pragma unroll
            for (int i = 0; i < 4; i++)
                #pragma unroll
                for (int j = 0; j < 2; j++)
                    acc[i][j] = __builtin_amdgcn_mfma_f32_16x16x32_bf16(af[i], bf[j], acc[i][j], 0, 0, 0);
        }
    }

    #pragma unroll
    for (int i = 0; i < 4; i++)
        #pragma unroll
        for (int r = 0; r < 4; r++) {
            size_t row = (size_t)(bm + wr * 64 + i * 16 + quad * 4 + r);
            #pragma unroll
            for (int j = 0; j < 2; j++) {
                int col = bn + wc * 32 + j * 16 + x;
                dst[row * D_ + col] = acc[i][j][r];
            }
        }
}

// ---------------------------------------------------------------------------
// LayerNorm helpers / kernels.
// ---------------------------------------------------------------------------
__device__ __forceinline__ float wave_sum64(float v) {
    #pragma unroll
    for (int off = 32; off > 0; off >>= 1) v += __shfl_xor(v, off, 64);
    return v;
}
__device__ __forceinline__ void load8(const float* p, float* v) {
    *(float4*)&v[0] = *(const float4*)p;
    *(float4*)&v[4] = *(const float4*)(p + 4);
}
__device__ __forceinline__ void load8(const ushort* p, float* v) {
    short8 s = *(const short8*)p;
    #pragma unroll
    for (int i = 0; i < 8; i++) v[i] = bf2f((ushort)s[i]);
}
__device__ __forceinline__ void store8(float* p, const float* v) {
    *(float4*)p       = make_float4(v[0], v[1], v[2], v[3]);
    *(float4*)(p + 4) = make_float4(v[4], v[5], v[6], v[7]);
}
__device__ __forceinline__ void store8(ushort* p, const float* v) {
    short8 s;
    #pragma unroll
    for (int i = 0; i < 8; i++) s[i] = f2bf(v[i]);
    *(short8*)p = s;
}
__device__ __forceinline__ void ln_core(float* v, int lane,
    const float* g, const float* be, float* t) {
    float s = 0.f;
    #pragma unroll
    for (int i = 0; i < 8; i++) s += v[i];
    float mean = wave_sum64(s) * (1.0f / 512.0f);
    float vs = 0.f;
    #pragma unroll
    for (int i = 0; i < 8; i++) { float d = v[i] - mean; vs += d * d; }
    float var = wave_sum64(vs) * (1.0f / 512.0f);
    float r = rsqrtf(var + 1e-5f);
    const int c = lane * 8;
    #pragma unroll
    for (int i = 0; i < 8; i++) t[i] = (v[i] - mean) * r * g[c + i] + be[c + i];
}

template <typename TA, typename TO>
__global__ __launch_bounds__(256) void addln_kernel(
    const TA* __restrict__ a,
    const float* __restrict__ g, const float* __restrict__ be,
    TO* __restrict__ out)
{
    const int lane = threadIdx.x & 63;
    const int row  = blockIdx.x * 4 + (threadIdx.x >> 6);
    const size_t base = (size_t)row * D_ + lane * 8;
    float v[8], t[8];
    load8(a + base, v);
    ln_core(v, lane, g, be, t);
    store8(out + base, t);
}

// out = LN(a + p0 + p1 + bias)  -- split-K GEMM combine fused into Add+LN
template <typename TA, typename TO>
__global__ __launch_bounds__(256) void ln_split_kernel(
    const TA* __restrict__ a,
    const float* __restrict__ p0, const float* __restrict__ p1,
    const float* __restrict__ bias,
    const float* __restrict__ g, const float* __restrict__ be,
    TO* __restrict__ out)
{
    const int lane = threadIdx.x & 63;
    const int row  = blockIdx.x * 4 + (threadIdx.x >> 6);
    const size_t base = (size_t)row * D_ + lane * 8;
    float v[8], w0[8], w1[8], t[8];
    load8(a + base, v);
    load8(p0 + base, w0);
    load8(p1 + base, w1);
    const int c = lane * 8;
    #pragma unroll
    for (int i = 0; i < 8; i++) v[i] += w0[i] + w1[i] + bias[c + i];
    ln_core(v, lane, g, be, t);
    store8(out + base, t);
}

// ---------------------------------------------------------------------------
// Generic bf16 512x512 transpose (weight prep). Grid (8,8).
// ---------------------------------------------------------------------------
__global__ __launch_bounds__(256) void transpose512_kernel(
    const ushort* __restrict__ in, ushort* __restrict__ out)
{
    __shared__ ushort T[64][72];
    const int t  = threadIdx.x;
    const int r0 = blockIdx.y * 64, c0 = blockIdx.x * 64;
    {
        int row = t >> 2, col = (t & 3) * 16;
        const ushort* s = in + (size_t)(r0 + row) * 512 + c0 + col;
        *(short8*)&T[row][col]     = *(const short8*)s;
        *(short8*)&T[row][col + 8] = *(const short8*)(s + 8);
    }
    __syncthreads();
    {
        int d = t >> 2, sc = (t & 3) * 16;
        ushort tmp[16];
        #pragma unroll
        for (int k = 0; k < 16; k++) tmp[k] = T[sc + k][d];
        ushort* dptr = out + (size_t)(c0 + d) * 512 + r0 + sc;
        *(short8*)dptr       = *(const short8*)&tmp[0];
        *(short8*)(dptr + 8) = *(const short8*)&tmp[8];
    }
}

// ---------------------------------------------------------------------------
// bfuse[n] = sum_m gl_w[n][m] * out_proj_b[m] + gl_b[n]  (fp32). Wave/row.
// ---------------------------------------------------------------------------
__global__ __launch_bounds__(256) void fuse_bias_kernel(
    const float* __restrict__ gl_w, const float* __restrict__ opb,
    const float* __restrict__ gl_b, float* __restrict__ bf)
{
    const int lane = threadIdx.x & 63;
    const int row  = blockIdx.x * 4 + (threadIdx.x >> 6);
    float s = 0.f;
    #pragma unroll
    for (int i = 0; i < 8; i++) {
        int m = lane * 8 + i;
        s += gl_w[(size_t)row * 1024 + m] * opb[m];
    }
    s = wave_sum64(s);
    if (lane == 0) bf[row] = s + gl_b[row];
}

// ---------------------------------------------------------------------------
// Vectorized RoPE (+SCQ scale on q) in place on q|k buffer (ld 1024).
// Thread = (bs, h, d8 in 0..3): handles dims [d8*8,+8) pairs with +32.
// ---------------------------------------------------------------------------
__global__ __launch_bounds__(256) void rope_kernel(ushort* __restrict__ qk)
{
    int idx = blockIdx.x * 256 + threadIdx.x;   // < B*S*H*4
    int d8 = idx & 3;
    int h  = (idx >> 2) & 7;
    int bs = idx >> 5;
    int pos = bs & (S_ - 1);
    ushort* base = qk + (size_t)bs * QKLD + h * 64 + d8 * 8;
    float q1[8], q2[8], k1[8], k2[8];
    load8(base, q1);       load8(base + 32, q2);
    load8(base + 512, k1); load8(base + 544, k2);
    float oq1[8], oq2[8], ok1[8], ok2[8];
    #pragma unroll
    for (int i = 0; i < 8; i++) {
        int d = d8 * 8 + i;
        float inv_freq = exp2f(-(float)d * (2.0f / 64.0f) * 13.287712379549449f);
        float ang = (float)pos * inv_freq;
        float sn, cs;
        __sincosf(ang, &sn, &cs);
        oq1[i] = (q1[i] * cs - q2[i] * sn) * SCQ;
        oq2[i] = (q2[i] * cs + q1[i] * sn) * SCQ;
        ok1[i] = k1[i] * cs - k2[i] * sn;
        ok2[i] = k2[i] * cs + k1[i] * sn;
    }
    store8(base, oq1);       store8(base + 32, oq2);
    store8(base + 512, ok1); store8(base + 544, ok2);
}

// ---------------------------------------------------------------------------
// Merged attention (global z=0 / local z=1). 32x32x16 MFMA, S^T layout,
// no-max exp2 softmax, register-resident P (bit-swapped V^T key order makes
// PV B-fragments consecutive S^T regs -- no cross-lane traffic), in-block
// split-K over 2 wave-pairs. Additive partials combined once via LDS.
// ---------------------------------------------------------------------------
__global__ __launch_bounds__(256) void attn_kernel(
    const ushort* __restrict__ qkG, const ushort* __restrict__ vtG,
    const ushort* __restrict__ qkL, const ushort* __restrict__ vtL,
    ushort* __restrict__ cat)
{
    __shared__ short KsS[2][64 * 64];
    __shared__ short VtS[2][64 * 64];
    __shared__ float Lw[4][32];

    const int LOCAL = blockIdx.z;
    const ushort* qk = LOCAL ? qkL : qkG;
    const ushort* vt = LOCAL ? vtL : vtG;
    ushort* outp = cat + (LOCAL ? D_ : 0);

    const int tid  = threadIdx.x;
    const int w    = tid >> 6;
    const int lane = tid & 63;
    const int hl   = lane >> 5;
    const int c    = lane & 31;
    const int ks   = w >> 1;
    const int qh   = w & 1;
    const int bh = blockIdx.y;
    const int b = bh >> 3, h = bh & 7;
    const int qbase = blockIdx.x * 64;
    const int q0 = qbase + qh * 32;
    const size_t bS = (size_t)b * S_;
    const size_t vbase = (size_t)bh * DH_;

    // Q fragments (B-operand layout); global folds 0.125*log2e, local pre-scaled
    short8 aq[4];
    {
        const ushort* qp = qk + (bS + q0 + c) * QKLD + h * 64;
        #pragma unroll
        for (int kc = 0; kc < 4; kc++) {
            short8 raw = *(const short8*)(qp + kc * 16 + hl * 8);
            if (LOCAL) aq[kc] = raw;
            else {
                #pragma unroll
                for (int j = 0; j < 8; j++) aq[kc][j] = f2bf(bf2f((ushort)raw[j]) * SCQ);
            }
        }
    }

    f32x16 ot[2];
    ot[0] = (f32x16)0.f; ot[1] = (f32x16)0.f;
    float lp = 0.f;

    const int NIT = LOCAL ? 2 : 16;
    for (int it = 0; it < NIT; it++) {
        const int tile  = ks * NIT + it;
        const int kbase = LOCAL ? ((qbase >> 7) * 128 - 128 + tile * 64) : tile * 64;
        const bool active = !LOCAL || (kbase >= 0 && kbase <= qbase + 63);
        __syncthreads();
        if (active) {
            #pragma unroll
            for (int cc = 0; cc < 4; cc++) {
                int row = qh * 32 + cc * 8 + (lane >> 3);
                int cg  = (lane & 7) ^ (lane >> 3);
                gload_lds16(qk + (bS + kbase + row) * QKLD + 512 + h * 64 + cg * 8,
                            &KsS[ks][(qh * 32 + cc * 8) * 64]);
                gload_lds16(vt + (vbase + row) * S_ + kbase + cg * 8,
                            &VtS[ks][(qh * 32 + cc * 8) * 64]);
            }
        }
        __syncthreads();
        if (!active) continue;
        const bool diag = LOCAL && (kbase == qbase);

        // S^T = K Q^T : D[key][q]
        f32x16 e0 = (f32x16)0.f, e1 = (f32x16)0.f;
        #pragma unroll
        for (int kc = 0; kc < 4; kc++) {
            int pcg = (kc * 2 + hl) ^ (c & 7);
            short8 ak0 = *(const short8*)&KsS[ks][c * 64 + pcg * 8];
            e0 = __builtin_amdgcn_mfma_f32_32x32x16_bf16(ak0, aq[kc], e0, 0, 0, 0);
            short8 ak1 = *(const short8*)&KsS[ks][(32 + c) * 64 + pcg * 8];
            e1 = __builtin_amdgcn_mfma_f32_32x32x16_bf16(ak1, aq[kc], e1, 0, 0, 0);
        }

        // p = exp2(s') (scores bounded; no max), diag mask, per-lane l partial
        const int qi = q0 + c;
        #pragma unroll
        for (int mt = 0; mt < 2; mt++) {
            f32x16& e = mt ? e1 : e0;
            #pragma unroll
            for (int r = 0; r < 16; r++) {
                float p = exp2f(e[r]);
                if (diag) {
                    int key = kbase + mt * 32 + (r & 3) + 8 * (r >> 2) + 4 * hl;
                    if (key > qi) p = 0.f;
                }
                e[r] = p;
                lp += p;
            }
        }

        // O^T += V^T P^T. Bit-swapped V^T key order => B-frag for call t is
        // regs e[(t<2?e0:e1)][8*(t&1)+0..7], packed pairwise. No shuffles.
        #pragma unroll
        for (int t = 0; t < 4; t++) {
            const f32x16& e = (t < 2) ? e0 : e1;
            const int rb = 8 * (t & 1);
            uint4 u;
            u.x = pack_bf_trunc(e[rb + 0], e[rb + 1]);
            u.y = pack_bf_trunc(e[rb + 2], e[rb + 3]);
            u.z = pack_bf_trunc(e[rb + 4], e[rb + 5]);
            u.w = pack_bf_trunc(e[rb + 6], e[rb + 7]);
            short8 bp = *(short8*)&u;
            #pragma unroll
            for (int dt = 0; dt < 2; dt++) {
                int row = dt * 32 + c;
                int pcg = (t * 2 + hl) ^ (c & 7);
                short8 av = *(const short8*)&VtS[ks][row * 64 + pcg * 8];
                ot[dt] = __builtin_amdgcn_mfma_f32_32x32x16_bf16(av, bp, ot[dt], 0, 0, 0);
            }
        }
    }

    // l for q=c over my key-chunk
    lp += __shfl_xor(lp, 32, 64);
    if (hl == 0) Lw[w][c] = lp;
    __syncthreads();   // tile reads done; staging bufs free; Lw visible

    // cross-pair combine: waves 2,3 dump O^T partials into dead KsS region
    float* scr = (float*)&KsS[0][0];
    if (w >= 2) {
        float* dst = scr + (w - 2) * 2048;
        #pragma unroll
        for (int dt = 0; dt < 2; dt++)
            #pragma unroll
            for (int r = 0; r < 16; r++)
                dst[(dt * 16 + r) * 64 + lane] = ot[dt][r];
    }
    __syncthreads();
    if (w < 2) {
        const float* srcp = scr + w * 2048;
        #pragma unroll
        for (int dt = 0; dt < 2; dt++)
            #pragma unroll
            for (int r = 0; r < 16; r++)
                ot[dt][r] += srcp[(dt * 16 + r) * 64 + lane];
        float inv = 1.0f / (Lw[w][c] + Lw[w + 2][c]);

        short* tr = (short*)&VtS[0][0] + w * 2304;
        #pragma unroll
        for (int dt = 0; dt < 2; dt++)
            #pragma unroll
            for (int rq = 0; rq < 4; rq++) {
                uint2 pkv;
                pkv.x = pack_bf_trunc(ot[dt][rq * 4 + 0] * inv, ot[dt][rq * 4 + 1] * inv);
                pkv.y = pack_bf_trunc(ot[dt][rq * 4 + 2] * inv, ot[dt][rq * 4 + 3] * inv);
                *(uint2*)&tr[c * 72 + dt * 32 + 8 * rq + 4 * hl] = pkv;
            }
        asm volatile("s_waitcnt lgkmcnt(0)" ::: "memory");
        __builtin_amdgcn_wave_barrier();
        {
            int q  = lane >> 1;
            int d0 = (lane & 1) * 32;
            short8 v0 = *(const short8*)&tr[q * 72 + d0];
            short8 v1 = *(const short8*)&tr[q * 72 + d0 + 8];
            short8 v2 = *(const short8*)&tr[q * 72 + d0 + 16];
            short8 v3 = *(const short8*)&tr[q * 72 + d0 + 24];
            ushort* op = outp + (bS + q0 + q) * 1024 + h * 64 + d0;
            *(short8*)(op)      = v0;
            *(short8*)(op + 8)  = v1;
            *(short8*)(op + 16) = v2;
            *(short8*)(op + 24) = v3;
        }
    }
}

// ---------------------------------------------------------------------------
extern "C" void kernel_launch(void* const* d_in, const int* in_sizes, int n_in,
                              void* d_out, int out_size, void* d_ws, size_t ws_size,
                              hipStream_t stream)
{
    (void)in_sizes; (void)n_in; (void)out_size; (void)ws_size;
    const float* src        = (const float*)d_in[0];
    const float* in_proj_w  = (const float*)d_in[1];
    const float* in_proj_b  = (const float*)d_in[2];
    const float* out_proj_w = (const float*)d_in[3];
    const float* out_proj_b = (const float*)d_in[4];
    const float* ln_g       = (const float*)d_in[5];
    const float* ln_b       = (const float*)d_in[6];
    const float* qkv_w      = (const float*)d_in[7];
    const float* to_out_w   = (const float*)d_in[8];
    const float* gl_w       = (const float*)d_in[9];
    const float* gl_b       = (const float*)d_in[10];
    const float* norm1_g    = (const float*)d_in[11];
    const float* norm1_b    = (const float*)d_in[12];
    const float* lin1_w     = (const float*)d_in[13];
    const float* lin1_b     = (const float*)d_in[14];
    const float* lin2_w     = (const float*)d_in[15];
    const float* lin2_b     = (const float*)d_in[16];
    const float* norm2_g    = (const float*)d_in[17];
    const float* norm2_b    = (const float*)d_in[18];
    float* out = (float*)d_out;

    // --- workspace (ushort units), ~104 MB total ---
    ushort* ws16   = (ushort*)d_ws;
    ushort* src_bf = ws16;                          // 8192*512
    ushort* wi_bf  = src_bf + (size_t)MR_ * D_;
    ushort* wq_bf  = wi_bf  + TRD * D_;
    ushort* wo_bf  = wq_bf  + TRD * D_;
    ushort* wt_bf  = wo_bf  + D_ * D_;
    ushort* wg_bf  = wt_bf  + D_ * D_;
    ushort* w1_bf  = wg_bf  + D_ * 2 * D_;
    ushort* w2_bf  = w1_bf  + FF_ * D_;
    ushort* opwT   = w2_bf  + D_ * FF_;
    ushort* towT   = opwT   + D_ * D_;
    ushort* wcat   = towT   + D_ * D_;              // 512*1024
    float*  bfuse  = (float*)(wcat + D_ * 2 * D_);  // 512 fp32
    ushort* buf1   = (ushort*)(bfuse + D_);         // 8192*512 (x)
    ushort* h1b    = buf1 + (size_t)MR_ * D_;       // 8192*512
    ushort* qkG    = h1b  + (size_t)MR_ * D_;       // 8192*1024
    ushort* vtg    = qkG  + (size_t)MR_ * QKLD;     // 8192*512
    ushort* qkL    = vtg  + (size_t)MR_ * D_;       // 8192*1024
    ushort* vtl    = qkL  + (size_t)MR_ * QKLD;     // 8192*512
    ushort* cat    = vtl  + (size_t)MR_ * D_;       // 8192*1024
    // overlays (regions dead by the time they're reused):
    float*  part   = (float*)qkG;                   // 2 x 8192*512 fp32 partials
    ushort* ff1    = qkL + (size_t)MR_ * D_;        // 8192*2048 over qkL-tail+vtl+cat

    dim3 blk256(256);

    // 0. fp32 -> bf16 conversions
    CvtJobs jobs;
    jobs.s[0] = src;        jobs.d[0] = src_bf; jobs.n[0] = MR_ * D_;
    jobs.s[1] = in_proj_w;  jobs.d[1] = wi_bf;  jobs.n[1] = TRD * D_;
    jobs.s[2] = qkv_w;      jobs.d[2] = wq_bf;  jobs.n[2] = TRD * D_;
    jobs.s[3] = out_proj_w; jobs.d[3] = wo_bf;  jobs.n[3] = D_ * D_;
    jobs.s[4] = to_out_w;   jobs.d[4] = wt_bf;  jobs.n[4] = D_ * D_;
    jobs.s[5] = gl_w;       jobs.d[5] = wg_bf;  jobs.n[5] = D_ * 2 * D_;
    jobs.s[6] = lin1_w;     jobs.d[6] = w1_bf;  jobs.n[6] = FF_ * D_;
    jobs.s[7] = lin2_w;     jobs.d[7] = w2_bf;  jobs.n[7] = D_ * FF_;
    cvt_kernel<<<dim3(4096), blk256, 0, stream>>>(jobs);

    // 0b. weight prep: wcat = [G1@OPW | G2@TOW], bias fold
    transpose512_kernel<<<dim3(8, 8), blk256, 0, stream>>>(wo_bf, opwT);
    transpose512_kernel<<<dim3(8, 8), blk256, 0, stream>>>(wt_bf, towT);
    gemm_bf16_kernel<<<dim3(8, 4), blk256, 0, stream>>>(
        wg_bf, 2 * D_, opwT, nullptr, wcat, 2 * D_, nullptr, D_, 0);
    gemm_bf16_kernel<<<dim3(8, 4), blk256, 0, stream>>>(
        wg_bf + D_, 2 * D_, towT, nullptr, wcat + D_, 2 * D_, nullptr, D_, 0);
    fuse_bias_kernel<<<dim3(D_ / 4), blk256, 0, stream>>>(gl_w, out_proj_b, gl_b, bfuse);

    // 1. global qkv = src @ in_proj^T + b  -> qkG (q|k) + vtg (V^T, permuted)
    gemm_bf16_kernel<<<dim3(TRD / 64, MR_ / 128), blk256, 0, stream>>>(
        src_bf, D_, wi_bf, in_proj_b, qkG, QKLD, vtg, D_, 0);
    // 2. x = LN(src) -> buf1
    addln_kernel<float, ushort><<<dim3(MR_ / 4), blk256, 0, stream>>>(
        src, ln_g, ln_b, buf1);
    // 3. local qkv = x @ qkv_w^T -> qkL + vtl
    gemm_bf16_kernel<<<dim3(TRD / 64, MR_ / 128), blk256, 0, stream>>>(
        buf1, D_, wq_bf, nullptr, qkL, QKLD, vtl, D_, 0);
    // 4. RoPE (+SCQ on q) on qkL
    rope_kernel<<<dim3((B_ * S_ * H_ * 4) / 256), blk256, 0, stream>>>(qkL);
    // 5. merged attention -> cat [go_pre | lo_pre]
    attn_kernel<<<dim3(S_ / 64, B_ * H_, 2), blk256, 0, stream>>>(
        qkG, vtg, qkL, vtl, cat);
    // 6. src2 partials = cat @ wcat^T (split-K x2, K=1024)
    gemm_bf16_splitk_kernel<<<dim3(D_ / 64, MR_ / 128, 2), blk256, 0, stream>>>(
        cat, 2 * D_, wcat, part, 2 * D_);
    // 7. h1 = LN(src + p0 + p1 + bfuse) -> h1b
    ln_split_kernel<float, ushort><<<dim3(MR_ / 4), blk256, 0, stream>>>(
        src, part, part + (size_t)MR_ * D_, bfuse, norm1_g, norm1_b, h1b);
    // 8. ff1 = relu(h1 @ lin1^T + b)
    gemm_bf16_kernel<<<dim3(FF_ / 64, MR_ / 128), blk256, 0, stream>>>(
        h1b, D_, w1_bf, lin1_b, ff1, FF_, nullptr, D_, 1);
    // 9. ff2 partials = ff1 @ lin2^T (split-K x2, K=2048)
    gemm_bf16_splitk_kernel<<<dim3(D_ / 64, MR_ / 128, 2), blk256, 0, stream>>>(
        ff1, FF_, w2_bf, part, FF_);
    // 10. out = LN(h1 + p0 + p1 + lin2_b) -> d_out (fp32)
    ln_split_kernel<ushort, float><<<dim3(MR_ / 4), blk256, 0, stream>>>(
        h1b, part, part + (size_t)MR_ * D_, lin2_b, norm2_g, norm2_b, out);
}